// Round 3
// baseline (537.501 us; speedup 1.0000x reference)
//
#include <hip/hip_runtime.h>

// ---------------------------------------------------------------------------
// GNN: 2x SAGEConv(mean) + ReLU, global mean pool, 2-layer MLP classifier.
// N=50000 nodes, E=600000 edges, F=H=128, 64 graphs. All fp32.
// R2: hierarchical scan (110us -> ~10us).
// R3: fused global-mean-pool into layer-2 k_lin epilogue; h2 never hits HBM.
//     (k_pool was 73us latency-bound; pooling now costs ~one LDS reduce +
//      128 global atomics per 64-node block.)
// ---------------------------------------------------------------------------

// ---- CSR build ------------------------------------------------------------

__global__ __launch_bounds__(256) void k_deg(const int* __restrict__ ei, int* __restrict__ cnt, int E) {
  int e = blockIdx.x * 256 + threadIdx.x;
  if (e < E) atomicAdd(&cnt[ei[E + e]], 1);  // dst = ei[E+e]
}

__global__ __launch_bounds__(256) void k_gcnt(const int* __restrict__ batch, int* __restrict__ gcnt, int N) {
  int i = blockIdx.x * 256 + threadIdx.x;
  if (i < N) atomicAdd(&gcnt[batch[i]], 1);
}

// stage 1: per-block (1024 elems) local exclusive scan; block sums to bsum
__global__ __launch_bounds__(256) void k_scan_local(const int* __restrict__ cnt, int* __restrict__ off,
                                                    int* __restrict__ bsum, int n) {
  __shared__ int s[256];
  int t = threadIdx.x;
  int base = blockIdx.x * 1024 + t * 4;
  int v0 = 0, v1 = 0, v2 = 0, v3 = 0;
  if (base + 3 < n) {
    int4 q = *(const int4*)(cnt + base);
    v0 = q.x; v1 = q.y; v2 = q.z; v3 = q.w;
  } else {
    if (base + 0 < n) v0 = cnt[base + 0];
    if (base + 1 < n) v1 = cnt[base + 1];
    if (base + 2 < n) v2 = cnt[base + 2];
    if (base + 3 < n) v3 = cnt[base + 3];
  }
  s[t] = v0 + v1 + v2 + v3;
  __syncthreads();
  for (int d = 1; d < 256; d <<= 1) {
    int x = (t >= d) ? s[t - d] : 0;
    __syncthreads();
    s[t] += x;
    __syncthreads();
  }
  int pre = (t == 0) ? 0 : s[t - 1];
  if (t == 255) bsum[blockIdx.x] = s[255];
  int e0 = pre, e1 = e0 + v0, e2 = e1 + v1, e3 = e2 + v2;
  if (base + 3 < n) {
    *(int4*)(off + base) = make_int4(e0, e1, e2, e3);
  } else {
    if (base + 0 < n) off[base + 0] = e0;
    if (base + 1 < n) off[base + 1] = e1;
    if (base + 2 < n) off[base + 2] = e2;
    if (base + 3 < n) off[base + 3] = e3;
  }
}

// stage 2: scan the block sums (nb <= 256), write total to totalOut (=off[n])
__global__ __launch_bounds__(256) void k_scan_mid(int* __restrict__ bsum, int* __restrict__ totalOut, int nb) {
  __shared__ int s[256];
  int t = threadIdx.x;
  s[t] = (t < nb) ? bsum[t] : 0;
  __syncthreads();
  for (int d = 1; d < 256; d <<= 1) {
    int x = (t >= d) ? s[t - d] : 0;
    __syncthreads();
    s[t] += x;
    __syncthreads();
  }
  if (t < nb) bsum[t] = (t == 0) ? 0 : s[t - 1];
  if (t == 255) totalOut[0] = s[255];
}

// stage 3: add block prefix; also init fill cursor = off
__global__ __launch_bounds__(256) void k_scan_add(int* __restrict__ off, int* __restrict__ cursor,
                                                  const int* __restrict__ bsum, int n) {
  int base = blockIdx.x * 1024 + threadIdx.x * 4;
  int b = bsum[blockIdx.x];
  if (base + 3 < n) {
    int4 q = *(const int4*)(off + base);
    q.x += b; q.y += b; q.z += b; q.w += b;
    *(int4*)(off + base) = q;
    *(int4*)(cursor + base) = q;
  } else {
    for (int k = 0; k < 4; ++k)
      if (base + k < n) {
        int v = off[base + k] + b;
        off[base + k] = v;
        cursor[base + k] = v;
      }
  }
}

__global__ __launch_bounds__(256) void k_fill(const int* __restrict__ ei, int* __restrict__ cursor,
                                              int* __restrict__ col, int E) {
  int e = blockIdx.x * 256 + threadIdx.x;
  if (e < E) {
    int d = ei[E + e];
    int p = atomicAdd(&cursor[d], 1);
    col[p] = ei[e];          // src
  }
}

// ---- mean aggregation: T[i,:] = mean_{j in N(i)} X[j,:] -------------------

__global__ __launch_bounds__(256) void k_agg(const float* __restrict__ X, const int* __restrict__ off,
                                             const int* __restrict__ col, float* __restrict__ T, int N) {
  int wid = (blockIdx.x * 256 + threadIdx.x) >> 6;  // one wave per node
  int lane = threadIdx.x & 63;
  if (wid >= N) return;
  int o0 = off[wid], o1 = off[wid + 1];
  int deg = o1 - o0;
  float ax = 0.f, ay = 0.f;
  for (int base = 0; base < deg; base += 64) {
    int cnt = min(64, deg - base);
    int cv = (lane < cnt) ? col[o0 + base + lane] : 0;
    int i = 0;
    for (; i + 4 <= cnt; i += 4) {
      int s0 = __shfl(cv, i), s1 = __shfl(cv, i + 1), s2 = __shfl(cv, i + 2), s3 = __shfl(cv, i + 3);
      float2 v0 = *(const float2*)(X + (size_t)s0 * 128 + lane * 2);
      float2 v1 = *(const float2*)(X + (size_t)s1 * 128 + lane * 2);
      float2 v2 = *(const float2*)(X + (size_t)s2 * 128 + lane * 2);
      float2 v3 = *(const float2*)(X + (size_t)s3 * 128 + lane * 2);
      ax += v0.x + v1.x + v2.x + v3.x;
      ay += v0.y + v1.y + v2.y + v3.y;
    }
    for (; i < cnt; ++i) {
      int s0 = __shfl(cv, i);
      float2 v0 = *(const float2*)(X + (size_t)s0 * 128 + lane * 2);
      ax += v0.x;
      ay += v0.y;
    }
  }
  float sc = 1.0f / (float)max(deg, 1);
  float2 r;
  r.x = ax * sc;
  r.y = ay * sc;
  *(float2*)(T + (size_t)wid * 128 + lane * 2) = r;
}

// ---- fused linear: H = relu(A @ Wl.T + X @ Wr.T + b) ----------------------
// A,X: [N,128]; Wl,Wr: [128,128] row-major.
// mode 0: write H to OUT.
// mode 1: do NOT write H; instead accumulate per-graph mean-pool partial sums
//         into gsum (batch is sorted; most 64-node blocks span one graph).
// Tile: 64 nodes x 128 outputs per block (256 threads), 4x8 acc per thread.

__global__ __launch_bounds__(256) void k_lin(const float* __restrict__ A, const float* __restrict__ X,
                                             const float* __restrict__ Wl, const float* __restrict__ Wr,
                                             const float* __restrict__ bias, float* OUT,
                                             const int* __restrict__ batch, float* __restrict__ gsum,
                                             int N, int mode) {
  __shared__ float As[64][36];    // [node][k] padded
  __shared__ float Ws[32][132];   // [k][h] transposed, padded
  int tid = threadIdx.x;
  int tx = tid & 15;              // h group: h0 = tx*8
  int ty = tid >> 4;              // node group: n0 = ty*4
  int rowBase = blockIdx.x * 64;
  float acc[4][8];
#pragma unroll
  for (int i = 0; i < 4; ++i)
#pragma unroll
    for (int j = 0; j < 8; ++j) acc[i][j] = 0.f;

  for (int c = 0; c < 8; ++c) {
    const float* S = (c < 4) ? A : X;
    const float* W = (c < 4) ? Wl : Wr;
    int kOff = (c & 3) * 32;
    __syncthreads();
    // stage A chunk: 64 rows x 32 k
#pragma unroll
    for (int n = 0; n < 2; ++n) {
      int idx = tid + n * 256;
      int r = idx >> 3, q = idx & 7;
      int gr = min(rowBase + r, N - 1);
      const float4 v = *(const float4*)(S + (size_t)gr * 128 + kOff + q * 4);
      *(float4*)(&As[r][q * 4]) = v;
    }
    // stage W chunk transposed: Ws[k][h] = W[h][kOff+k]
#pragma unroll
    for (int n = 0; n < 4; ++n) {
      int idx = tid + n * 256;
      int h = idx >> 3, q = idx & 7;
      const float4 v = *(const float4*)(W + (size_t)h * 128 + kOff + q * 4);
      Ws[q * 4 + 0][h] = v.x;
      Ws[q * 4 + 1][h] = v.y;
      Ws[q * 4 + 2][h] = v.z;
      Ws[q * 4 + 3][h] = v.w;
    }
    __syncthreads();
#pragma unroll
    for (int kk = 0; kk < 32; ++kk) {
      float a[4];
#pragma unroll
      for (int i = 0; i < 4; ++i) a[i] = As[ty * 4 + i][kk];
      const float4 w0 = *(const float4*)(&Ws[kk][tx * 8]);
      const float4 w1 = *(const float4*)(&Ws[kk][tx * 8 + 4]);
      float w[8] = {w0.x, w0.y, w0.z, w0.w, w1.x, w1.y, w1.z, w1.w};
#pragma unroll
      for (int i = 0; i < 4; ++i)
#pragma unroll
        for (int j = 0; j < 8; ++j) acc[i][j] += a[i] * w[j];
    }
  }

  // bias + relu in registers
  int h0 = tx * 8;
  float b[8];
#pragma unroll
  for (int j = 0; j < 8; ++j) b[j] = bias[h0 + j];
#pragma unroll
  for (int i = 0; i < 4; ++i)
#pragma unroll
    for (int j = 0; j < 8; ++j) acc[i][j] = fmaxf(acc[i][j] + b[j], 0.f);

  if (mode == 0) {
#pragma unroll
    for (int i = 0; i < 4; ++i) {
      int row = rowBase + ty * 4 + i;
      if (row < N) {
        float4 r0 = {acc[i][0], acc[i][1], acc[i][2], acc[i][3]};
        float4 r1 = {acc[i][4], acc[i][5], acc[i][6], acc[i][7]};
        *(float4*)(OUT + (size_t)row * 128 + h0) = r0;
        *(float4*)(OUT + (size_t)row * 128 + h0 + 4) = r1;
      }
    }
  } else {
    // fused global-mean-pool partial sums
    __shared__ float ps[128];
    if (tid < 128) ps[tid] = 0.f;
    __syncthreads();
    int lastRow = min(rowBase + 63, N - 1);
    int g0 = batch[rowBase], g1 = batch[lastRow];
    if (g0 == g1) {
      float s[8];
#pragma unroll
      for (int j = 0; j < 8; ++j) s[j] = 0.f;
#pragma unroll
      for (int i = 0; i < 4; ++i) {
        int row = rowBase + ty * 4 + i;
        if (row < N) {
#pragma unroll
          for (int j = 0; j < 8; ++j) s[j] += acc[i][j];
        }
      }
#pragma unroll
      for (int j = 0; j < 8; ++j) atomicAdd(&ps[h0 + j], s[j]);
      __syncthreads();
      if (tid < 128) atomicAdd(&gsum[g0 * 128 + tid], ps[tid]);
    } else {
      // boundary block (rare): per-row atomics
#pragma unroll
      for (int i = 0; i < 4; ++i) {
        int row = rowBase + ty * 4 + i;
        if (row < N) {
          int g = batch[row];
#pragma unroll
          for (int j = 0; j < 8; ++j) atomicAdd(&gsum[g * 128 + h0 + j], acc[i][j]);
        }
      }
    }
  }
}

// ---- classifier -----------------------------------------------------------

__global__ __launch_bounds__(128) void k_cls1(const float* __restrict__ gsum, const int* __restrict__ gcnt,
                                              const float* __restrict__ Wc1, const float* __restrict__ bc1,
                                              float* __restrict__ z) {
  int g = blockIdx.x;   // 64 graphs
  int h = threadIdx.x;  // 128 hidden
  float inv = 1.0f / (float)max(gcnt[g], 1);
  float s = 0.f;
  for (int f = 0; f < 128; ++f) s += gsum[g * 128 + f] * Wc1[h * 128 + f];
  z[g * 128 + h] = fmaxf(s * inv + bc1[h], 0.f);
}

__global__ __launch_bounds__(128) void k_cls2(const float* __restrict__ z, const float* __restrict__ Wc2,
                                              const float* __restrict__ bc2, float* __restrict__ out) {
  __shared__ float red[128];
  int g = blockIdx.x;
  int t = threadIdx.x;
  red[t] = z[g * 128 + t] * Wc2[t];
  __syncthreads();
  for (int d = 64; d > 0; d >>= 1) {
    if (t < d) red[t] += red[t + d];
    __syncthreads();
  }
  if (t == 0) out[g] = red[0] + bc2[0];
}

// ---------------------------------------------------------------------------

extern "C" void kernel_launch(void* const* d_in, const int* in_sizes, int n_in,
                              void* d_out, int out_size, void* d_ws, size_t ws_size,
                              hipStream_t stream) {
  const float* x   = (const float*)d_in[0];
  const int*   ei  = (const int*)d_in[1];
  const int*   bat = (const int*)d_in[2];
  const float* W1l = (const float*)d_in[3];
  const float* b1l = (const float*)d_in[4];
  const float* W1r = (const float*)d_in[5];
  const float* W2l = (const float*)d_in[6];
  const float* b2l = (const float*)d_in[7];
  const float* W2r = (const float*)d_in[8];
  const float* Wc1 = (const float*)d_in[9];
  const float* bc1 = (const float*)d_in[10];
  const float* Wc2 = (const float*)d_in[11];
  const float* bc2 = (const float*)d_in[12];
  float* out = (float*)d_out;

  int N = in_sizes[0] / 128;
  int E = in_sizes[1] / 2;
  int nScanBlk = (N + 1023) / 1024;  // 49 for N=50000; must be <= 256

  char* ws = (char*)d_ws;
  size_t o = 0;
  auto alloc = [&](size_t bytes) {
    char* p = ws + o;
    o += (bytes + 255) & ~(size_t)255;
    return p;
  };
  int*   cursor = (int*)alloc((size_t)N * 4);            // deg counter, then fill cursor
  int*   off    = (int*)alloc((size_t)(N + 1) * 4);
  int*   col    = (int*)alloc((size_t)E * 4);
  int*   bsum   = (int*)alloc(256 * 4);
  float* T      = (float*)alloc((size_t)N * 128 * 4);    // agg scratch
  float* h1     = (float*)alloc((size_t)N * 128 * 4);
  float* gsum   = (float*)alloc(64 * 128 * 4 + 64 * 4);  // gsum + gcnt contiguous
  int*   gcnt   = (int*)(gsum + 64 * 128);
  float* z      = (float*)alloc(64 * 128 * 4);

  hipMemsetAsync(cursor, 0, (size_t)N * 4, stream);
  hipMemsetAsync(gsum, 0, 64 * 128 * 4 + 64 * 4, stream);

  k_deg<<<(E + 255) / 256, 256, 0, stream>>>(ei, cursor, E);
  k_gcnt<<<(N + 255) / 256, 256, 0, stream>>>(bat, gcnt, N);
  k_scan_local<<<nScanBlk, 256, 0, stream>>>(cursor, off, bsum, N);
  k_scan_mid<<<1, 256, 0, stream>>>(bsum, off + N, nScanBlk);
  k_scan_add<<<nScanBlk, 256, 0, stream>>>(off, cursor, bsum, N);
  k_fill<<<(E + 255) / 256, 256, 0, stream>>>(ei, cursor, col, E);

  // layer 1
  k_agg<<<(N + 3) / 4, 256, 0, stream>>>(x, off, col, T, N);
  k_lin<<<(N + 63) / 64, 256, 0, stream>>>(T, x, W1l, W1r, b1l, h1, bat, gsum, N, 0);
  // layer 2: h2 never materialized — pooled directly in the epilogue
  k_agg<<<(N + 3) / 4, 256, 0, stream>>>(h1, off, col, T, N);
  k_lin<<<(N + 63) / 64, 256, 0, stream>>>(T, h1, W2l, W2r, b2l, nullptr, bat, gsum, N, 1);

  // classifier
  k_cls1<<<64, 128, 0, stream>>>(gsum, gcnt, Wc1, bc1, z);
  k_cls2<<<64, 128, 0, stream>>>(z, Wc2, bc2, out);
}

// Round 4
// 309.256 us; speedup vs baseline: 1.7380x; 1.7380x over previous
//
#include <hip/hip_runtime.h>

// ---------------------------------------------------------------------------
// GNN: 2x SAGEConv(mean) + ReLU, global mean pool, 2-layer MLP classifier.
// N=50000 nodes, E=600000 edges, F=H=128, 64 graphs. All fp32.
// R2: hierarchical scan (110us -> ~10us).
// R3: fused global-mean-pool into layer-2 k_lin epilogue (h2 never hits HBM).
// R4: k_gcnt atomics (50K adds onto 64 addrs = 234us of same-address
//     serialization) replaced by 64-thread binary search on sorted batch.
// ---------------------------------------------------------------------------

// ---- CSR build ------------------------------------------------------------

__global__ __launch_bounds__(256) void k_deg(const int* __restrict__ ei, int* __restrict__ cnt, int E) {
  int e = blockIdx.x * 256 + threadIdx.x;
  if (e < E) atomicAdd(&cnt[ei[E + e]], 1);  // dst = ei[E+e]
}

// gcnt via binary search on sorted batch (no atomics)
__global__ __launch_bounds__(64) void k_gcnt_bs(const int* __restrict__ batch, int* __restrict__ gcnt,
                                                int N, int G) {
  int g = threadIdx.x;
  if (g >= G) return;
  int lo = 0, hi = N;
  while (lo < hi) { int mid = (lo + hi) >> 1; if (batch[mid] < g) lo = mid + 1; else hi = mid; }
  int a = lo;
  lo = 0; hi = N;
  while (lo < hi) { int mid = (lo + hi) >> 1; if (batch[mid] < g + 1) lo = mid + 1; else hi = mid; }
  gcnt[g] = lo - a;
}

// stage 1: per-block (1024 elems) local exclusive scan; block sums to bsum
__global__ __launch_bounds__(256) void k_scan_local(const int* __restrict__ cnt, int* __restrict__ off,
                                                    int* __restrict__ bsum, int n) {
  __shared__ int s[256];
  int t = threadIdx.x;
  int base = blockIdx.x * 1024 + t * 4;
  int v0 = 0, v1 = 0, v2 = 0, v3 = 0;
  if (base + 3 < n) {
    int4 q = *(const int4*)(cnt + base);
    v0 = q.x; v1 = q.y; v2 = q.z; v3 = q.w;
  } else {
    if (base + 0 < n) v0 = cnt[base + 0];
    if (base + 1 < n) v1 = cnt[base + 1];
    if (base + 2 < n) v2 = cnt[base + 2];
    if (base + 3 < n) v3 = cnt[base + 3];
  }
  s[t] = v0 + v1 + v2 + v3;
  __syncthreads();
  for (int d = 1; d < 256; d <<= 1) {
    int x = (t >= d) ? s[t - d] : 0;
    __syncthreads();
    s[t] += x;
    __syncthreads();
  }
  int pre = (t == 0) ? 0 : s[t - 1];
  if (t == 255) bsum[blockIdx.x] = s[255];
  int e0 = pre, e1 = e0 + v0, e2 = e1 + v1, e3 = e2 + v2;
  if (base + 3 < n) {
    *(int4*)(off + base) = make_int4(e0, e1, e2, e3);
  } else {
    if (base + 0 < n) off[base + 0] = e0;
    if (base + 1 < n) off[base + 1] = e1;
    if (base + 2 < n) off[base + 2] = e2;
    if (base + 3 < n) off[base + 3] = e3;
  }
}

// stage 2: scan the block sums (nb <= 256), write total to totalOut (=off[n])
__global__ __launch_bounds__(256) void k_scan_mid(int* __restrict__ bsum, int* __restrict__ totalOut, int nb) {
  __shared__ int s[256];
  int t = threadIdx.x;
  s[t] = (t < nb) ? bsum[t] : 0;
  __syncthreads();
  for (int d = 1; d < 256; d <<= 1) {
    int x = (t >= d) ? s[t - d] : 0;
    __syncthreads();
    s[t] += x;
    __syncthreads();
  }
  if (t < nb) bsum[t] = (t == 0) ? 0 : s[t - 1];
  if (t == 255) totalOut[0] = s[255];
}

// stage 3: add block prefix; also init fill cursor = off
__global__ __launch_bounds__(256) void k_scan_add(int* __restrict__ off, int* __restrict__ cursor,
                                                  const int* __restrict__ bsum, int n) {
  int base = blockIdx.x * 1024 + threadIdx.x * 4;
  int b = bsum[blockIdx.x];
  if (base + 3 < n) {
    int4 q = *(const int4*)(off + base);
    q.x += b; q.y += b; q.z += b; q.w += b;
    *(int4*)(off + base) = q;
    *(int4*)(cursor + base) = q;
  } else {
    for (int k = 0; k < 4; ++k)
      if (base + k < n) {
        int v = off[base + k] + b;
        off[base + k] = v;
        cursor[base + k] = v;
      }
  }
}

__global__ __launch_bounds__(256) void k_fill(const int* __restrict__ ei, int* __restrict__ cursor,
                                              int* __restrict__ col, int E) {
  int e = blockIdx.x * 256 + threadIdx.x;
  if (e < E) {
    int d = ei[E + e];
    int p = atomicAdd(&cursor[d], 1);
    col[p] = ei[e];          // src
  }
}

// ---- mean aggregation: T[i,:] = mean_{j in N(i)} X[j,:] -------------------

__global__ __launch_bounds__(256) void k_agg(const float* __restrict__ X, const int* __restrict__ off,
                                             const int* __restrict__ col, float* __restrict__ T, int N) {
  int wid = (blockIdx.x * 256 + threadIdx.x) >> 6;  // one wave per node
  int lane = threadIdx.x & 63;
  if (wid >= N) return;
  int o0 = off[wid], o1 = off[wid + 1];
  int deg = o1 - o0;
  float ax = 0.f, ay = 0.f;
  for (int base = 0; base < deg; base += 64) {
    int cnt = min(64, deg - base);
    int cv = (lane < cnt) ? col[o0 + base + lane] : 0;
    int i = 0;
    for (; i + 4 <= cnt; i += 4) {
      int s0 = __shfl(cv, i), s1 = __shfl(cv, i + 1), s2 = __shfl(cv, i + 2), s3 = __shfl(cv, i + 3);
      float2 v0 = *(const float2*)(X + (size_t)s0 * 128 + lane * 2);
      float2 v1 = *(const float2*)(X + (size_t)s1 * 128 + lane * 2);
      float2 v2 = *(const float2*)(X + (size_t)s2 * 128 + lane * 2);
      float2 v3 = *(const float2*)(X + (size_t)s3 * 128 + lane * 2);
      ax += v0.x + v1.x + v2.x + v3.x;
      ay += v0.y + v1.y + v2.y + v3.y;
    }
    for (; i < cnt; ++i) {
      int s0 = __shfl(cv, i);
      float2 v0 = *(const float2*)(X + (size_t)s0 * 128 + lane * 2);
      ax += v0.x;
      ay += v0.y;
    }
  }
  float sc = 1.0f / (float)max(deg, 1);
  float2 r;
  r.x = ax * sc;
  r.y = ay * sc;
  *(float2*)(T + (size_t)wid * 128 + lane * 2) = r;
}

// ---- fused linear: H = relu(A @ Wl.T + X @ Wr.T + b) ----------------------
// A,X: [N,128]; Wl,Wr: [128,128] row-major.
// mode 0: write H to OUT.
// mode 1: do NOT write H; instead accumulate per-graph mean-pool partial sums
//         into gsum (batch is sorted; most 64-node blocks span one graph).
// Tile: 64 nodes x 128 outputs per block (256 threads), 4x8 acc per thread.

__global__ __launch_bounds__(256) void k_lin(const float* __restrict__ A, const float* __restrict__ X,
                                             const float* __restrict__ Wl, const float* __restrict__ Wr,
                                             const float* __restrict__ bias, float* OUT,
                                             const int* __restrict__ batch, float* __restrict__ gsum,
                                             int N, int mode) {
  __shared__ float As[64][36];    // [node][k] padded
  __shared__ float Ws[32][132];   // [k][h] transposed, padded
  int tid = threadIdx.x;
  int tx = tid & 15;              // h group: h0 = tx*8
  int ty = tid >> 4;              // node group: n0 = ty*4
  int rowBase = blockIdx.x * 64;
  float acc[4][8];
#pragma unroll
  for (int i = 0; i < 4; ++i)
#pragma unroll
    for (int j = 0; j < 8; ++j) acc[i][j] = 0.f;

  for (int c = 0; c < 8; ++c) {
    const float* S = (c < 4) ? A : X;
    const float* W = (c < 4) ? Wl : Wr;
    int kOff = (c & 3) * 32;
    __syncthreads();
    // stage A chunk: 64 rows x 32 k
#pragma unroll
    for (int n = 0; n < 2; ++n) {
      int idx = tid + n * 256;
      int r = idx >> 3, q = idx & 7;
      int gr = min(rowBase + r, N - 1);
      const float4 v = *(const float4*)(S + (size_t)gr * 128 + kOff + q * 4);
      *(float4*)(&As[r][q * 4]) = v;
    }
    // stage W chunk transposed: Ws[k][h] = W[h][kOff+k]
#pragma unroll
    for (int n = 0; n < 4; ++n) {
      int idx = tid + n * 256;
      int h = idx >> 3, q = idx & 7;
      const float4 v = *(const float4*)(W + (size_t)h * 128 + kOff + q * 4);
      Ws[q * 4 + 0][h] = v.x;
      Ws[q * 4 + 1][h] = v.y;
      Ws[q * 4 + 2][h] = v.z;
      Ws[q * 4 + 3][h] = v.w;
    }
    __syncthreads();
#pragma unroll
    for (int kk = 0; kk < 32; ++kk) {
      float a[4];
#pragma unroll
      for (int i = 0; i < 4; ++i) a[i] = As[ty * 4 + i][kk];
      const float4 w0 = *(const float4*)(&Ws[kk][tx * 8]);
      const float4 w1 = *(const float4*)(&Ws[kk][tx * 8 + 4]);
      float w[8] = {w0.x, w0.y, w0.z, w0.w, w1.x, w1.y, w1.z, w1.w};
#pragma unroll
      for (int i = 0; i < 4; ++i)
#pragma unroll
        for (int j = 0; j < 8; ++j) acc[i][j] += a[i] * w[j];
    }
  }

  // bias + relu in registers
  int h0 = tx * 8;
  float b[8];
#pragma unroll
  for (int j = 0; j < 8; ++j) b[j] = bias[h0 + j];
#pragma unroll
  for (int i = 0; i < 4; ++i)
#pragma unroll
    for (int j = 0; j < 8; ++j) acc[i][j] = fmaxf(acc[i][j] + b[j], 0.f);

  if (mode == 0) {
#pragma unroll
    for (int i = 0; i < 4; ++i) {
      int row = rowBase + ty * 4 + i;
      if (row < N) {
        float4 r0 = {acc[i][0], acc[i][1], acc[i][2], acc[i][3]};
        float4 r1 = {acc[i][4], acc[i][5], acc[i][6], acc[i][7]};
        *(float4*)(OUT + (size_t)row * 128 + h0) = r0;
        *(float4*)(OUT + (size_t)row * 128 + h0 + 4) = r1;
      }
    }
  } else {
    // fused global-mean-pool partial sums
    __shared__ float ps[128];
    if (tid < 128) ps[tid] = 0.f;
    __syncthreads();
    int lastRow = min(rowBase + 63, N - 1);
    int g0 = batch[rowBase], g1 = batch[lastRow];
    if (g0 == g1) {
      float s[8];
#pragma unroll
      for (int j = 0; j < 8; ++j) s[j] = 0.f;
#pragma unroll
      for (int i = 0; i < 4; ++i) {
        int row = rowBase + ty * 4 + i;
        if (row < N) {
#pragma unroll
          for (int j = 0; j < 8; ++j) s[j] += acc[i][j];
        }
      }
#pragma unroll
      for (int j = 0; j < 8; ++j) atomicAdd(&ps[h0 + j], s[j]);
      __syncthreads();
      if (tid < 128) atomicAdd(&gsum[g0 * 128 + tid], ps[tid]);
    } else {
      // boundary block (rare): per-row atomics
#pragma unroll
      for (int i = 0; i < 4; ++i) {
        int row = rowBase + ty * 4 + i;
        if (row < N) {
          int g = batch[row];
#pragma unroll
          for (int j = 0; j < 8; ++j) atomicAdd(&gsum[g * 128 + h0 + j], acc[i][j]);
        }
      }
    }
  }
}

// ---- classifier -----------------------------------------------------------

__global__ __launch_bounds__(128) void k_cls1(const float* __restrict__ gsum, const int* __restrict__ gcnt,
                                              const float* __restrict__ Wc1, const float* __restrict__ bc1,
                                              float* __restrict__ z) {
  int g = blockIdx.x;   // 64 graphs
  int h = threadIdx.x;  // 128 hidden
  float inv = 1.0f / (float)max(gcnt[g], 1);
  float s = 0.f;
  for (int f = 0; f < 128; ++f) s += gsum[g * 128 + f] * Wc1[h * 128 + f];
  z[g * 128 + h] = fmaxf(s * inv + bc1[h], 0.f);
}

__global__ __launch_bounds__(128) void k_cls2(const float* __restrict__ z, const float* __restrict__ Wc2,
                                              const float* __restrict__ bc2, float* __restrict__ out) {
  __shared__ float red[128];
  int g = blockIdx.x;
  int t = threadIdx.x;
  red[t] = z[g * 128 + t] * Wc2[t];
  __syncthreads();
  for (int d = 64; d > 0; d >>= 1) {
    if (t < d) red[t] += red[t + d];
    __syncthreads();
  }
  if (t == 0) out[g] = red[0] + bc2[0];
}

// ---------------------------------------------------------------------------

extern "C" void kernel_launch(void* const* d_in, const int* in_sizes, int n_in,
                              void* d_out, int out_size, void* d_ws, size_t ws_size,
                              hipStream_t stream) {
  const float* x   = (const float*)d_in[0];
  const int*   ei  = (const int*)d_in[1];
  const int*   bat = (const int*)d_in[2];
  const float* W1l = (const float*)d_in[3];
  const float* b1l = (const float*)d_in[4];
  const float* W1r = (const float*)d_in[5];
  const float* W2l = (const float*)d_in[6];
  const float* b2l = (const float*)d_in[7];
  const float* W2r = (const float*)d_in[8];
  const float* Wc1 = (const float*)d_in[9];
  const float* bc1 = (const float*)d_in[10];
  const float* Wc2 = (const float*)d_in[11];
  const float* bc2 = (const float*)d_in[12];
  float* out = (float*)d_out;

  int N = in_sizes[0] / 128;
  int E = in_sizes[1] / 2;
  int nScanBlk = (N + 1023) / 1024;  // 49 for N=50000; must be <= 256

  char* ws = (char*)d_ws;
  size_t o = 0;
  auto alloc = [&](size_t bytes) {
    char* p = ws + o;
    o += (bytes + 255) & ~(size_t)255;
    return p;
  };
  int*   cursor = (int*)alloc((size_t)N * 4);            // deg counter, then fill cursor
  int*   off    = (int*)alloc((size_t)(N + 1) * 4);
  int*   col    = (int*)alloc((size_t)E * 4);
  int*   bsum   = (int*)alloc(256 * 4);
  float* T      = (float*)alloc((size_t)N * 128 * 4);    // agg scratch
  float* h1     = (float*)alloc((size_t)N * 128 * 4);
  float* gsum   = (float*)alloc(64 * 128 * 4 + 64 * 4);  // gsum + gcnt contiguous
  int*   gcnt   = (int*)(gsum + 64 * 128);
  float* z      = (float*)alloc(64 * 128 * 4);

  hipMemsetAsync(cursor, 0, (size_t)N * 4, stream);
  hipMemsetAsync(gsum, 0, 64 * 128 * 4, stream);

  k_deg<<<(E + 255) / 256, 256, 0, stream>>>(ei, cursor, E);
  k_gcnt_bs<<<1, 64, 0, stream>>>(bat, gcnt, N, 64);
  k_scan_local<<<nScanBlk, 256, 0, stream>>>(cursor, off, bsum, N);
  k_scan_mid<<<1, 256, 0, stream>>>(bsum, off + N, nScanBlk);
  k_scan_add<<<nScanBlk, 256, 0, stream>>>(off, cursor, bsum, N);
  k_fill<<<(E + 255) / 256, 256, 0, stream>>>(ei, cursor, col, E);

  // layer 1
  k_agg<<<(N + 3) / 4, 256, 0, stream>>>(x, off, col, T, N);
  k_lin<<<(N + 63) / 64, 256, 0, stream>>>(T, x, W1l, W1r, b1l, h1, bat, gsum, N, 0);
  // layer 2: h2 never materialized — pooled directly in the epilogue
  k_agg<<<(N + 3) / 4, 256, 0, stream>>>(h1, off, col, T, N);
  k_lin<<<(N + 63) / 64, 256, 0, stream>>>(T, h1, W2l, W2r, b2l, nullptr, bat, gsum, N, 1);

  // classifier
  k_cls1<<<64, 128, 0, stream>>>(gsum, gcnt, Wc1, bc1, z);
  k_cls2<<<64, 128, 0, stream>>>(z, Wc2, bc2, out);
}

// Round 5
// 229.703 us; speedup vs baseline: 2.3400x; 1.3463x over previous
//
#include <hip/hip_runtime.h>

// ---------------------------------------------------------------------------
// GNN: 2x SAGEConv(mean) + ReLU, global mean pool, 2-layer MLP classifier.
// N=50000 nodes, E=600000 edges, F=H=128, 64 graphs. fp32 in/out.
// R2: hierarchical scan (110us -> ~10us).
// R3: fused global-mean-pool into layer-2 linear epilogue (h2 never hits HBM).
// R4: gcnt via binary search (234us same-address atomics -> ~2us).
// R5: k_lin -> MFMA (bf16x3 split: hi*hi + hi*lo + lo*hi), weights pre-split
//     into fragment-linear buffers; column-partitioned waves so B frags are
//     read once per block (LDS floor ~6.5us/layer vs 46us row-partitioned).
// ---------------------------------------------------------------------------

typedef __attribute__((ext_vector_type(8))) short bf16x8;
typedef __attribute__((ext_vector_type(4))) float f32x4;

__device__ inline unsigned short f2bf(float f) {
  unsigned u = __float_as_uint(f);
  u += 0x7fff + ((u >> 16) & 1);  // round-to-nearest-even
  return (unsigned short)(u >> 16);
}
__device__ inline float bf2f(unsigned short h) { return __uint_as_float(((unsigned)h) << 16); }

// ---- CSR build ------------------------------------------------------------

__global__ __launch_bounds__(256) void k_deg(const int* __restrict__ ei, int* __restrict__ cnt, int E) {
  int e = blockIdx.x * 256 + threadIdx.x;
  if (e < E) atomicAdd(&cnt[ei[E + e]], 1);  // dst = ei[E+e]
}

// gcnt via binary search on sorted batch (no atomics)
__global__ __launch_bounds__(64) void k_gcnt_bs(const int* __restrict__ batch, int* __restrict__ gcnt,
                                                int N, int G) {
  int g = threadIdx.x;
  if (g >= G) return;
  int lo = 0, hi = N;
  while (lo < hi) { int mid = (lo + hi) >> 1; if (batch[mid] < g) lo = mid + 1; else hi = mid; }
  int a = lo;
  lo = 0; hi = N;
  while (lo < hi) { int mid = (lo + hi) >> 1; if (batch[mid] < g + 1) lo = mid + 1; else hi = mid; }
  gcnt[g] = lo - a;
}

__global__ __launch_bounds__(256) void k_scan_local(const int* __restrict__ cnt, int* __restrict__ off,
                                                    int* __restrict__ bsum, int n) {
  __shared__ int s[256];
  int t = threadIdx.x;
  int base = blockIdx.x * 1024 + t * 4;
  int v0 = 0, v1 = 0, v2 = 0, v3 = 0;
  if (base + 3 < n) {
    int4 q = *(const int4*)(cnt + base);
    v0 = q.x; v1 = q.y; v2 = q.z; v3 = q.w;
  } else {
    if (base + 0 < n) v0 = cnt[base + 0];
    if (base + 1 < n) v1 = cnt[base + 1];
    if (base + 2 < n) v2 = cnt[base + 2];
    if (base + 3 < n) v3 = cnt[base + 3];
  }
  s[t] = v0 + v1 + v2 + v3;
  __syncthreads();
  for (int d = 1; d < 256; d <<= 1) {
    int x = (t >= d) ? s[t - d] : 0;
    __syncthreads();
    s[t] += x;
    __syncthreads();
  }
  int pre = (t == 0) ? 0 : s[t - 1];
  if (t == 255) bsum[blockIdx.x] = s[255];
  int e0 = pre, e1 = e0 + v0, e2 = e1 + v1, e3 = e2 + v2;
  if (base + 3 < n) {
    *(int4*)(off + base) = make_int4(e0, e1, e2, e3);
  } else {
    if (base + 0 < n) off[base + 0] = e0;
    if (base + 1 < n) off[base + 1] = e1;
    if (base + 2 < n) off[base + 2] = e2;
    if (base + 3 < n) off[base + 3] = e3;
  }
}

__global__ __launch_bounds__(256) void k_scan_mid(int* __restrict__ bsum, int* __restrict__ totalOut, int nb) {
  __shared__ int s[256];
  int t = threadIdx.x;
  s[t] = (t < nb) ? bsum[t] : 0;
  __syncthreads();
  for (int d = 1; d < 256; d <<= 1) {
    int x = (t >= d) ? s[t - d] : 0;
    __syncthreads();
    s[t] += x;
    __syncthreads();
  }
  if (t < nb) bsum[t] = (t == 0) ? 0 : s[t - 1];
  if (t == 255) totalOut[0] = s[255];
}

__global__ __launch_bounds__(256) void k_scan_add(int* __restrict__ off, int* __restrict__ cursor,
                                                  const int* __restrict__ bsum, int n) {
  int base = blockIdx.x * 1024 + threadIdx.x * 4;
  int b = bsum[blockIdx.x];
  if (base + 3 < n) {
    int4 q = *(const int4*)(off + base);
    q.x += b; q.y += b; q.z += b; q.w += b;
    *(int4*)(off + base) = q;
    *(int4*)(cursor + base) = q;
  } else {
    for (int k = 0; k < 4; ++k)
      if (base + k < n) {
        int v = off[base + k] + b;
        off[base + k] = v;
        cursor[base + k] = v;
      }
  }
}

__global__ __launch_bounds__(256) void k_fill(const int* __restrict__ ei, int* __restrict__ cursor,
                                              int* __restrict__ col, int E) {
  int e = blockIdx.x * 256 + threadIdx.x;
  if (e < E) {
    int d = ei[E + e];
    int p = atomicAdd(&cursor[d], 1);
    col[p] = ei[e];          // src
  }
}

// ---- mean aggregation: T[i,:] = mean_{j in N(i)} X[j,:] -------------------

__global__ __launch_bounds__(256) void k_agg(const float* __restrict__ X, const int* __restrict__ off,
                                             const int* __restrict__ col, float* __restrict__ T, int N) {
  int wid = (blockIdx.x * 256 + threadIdx.x) >> 6;  // one wave per node
  int lane = threadIdx.x & 63;
  if (wid >= N) return;
  int o0 = off[wid], o1 = off[wid + 1];
  int deg = o1 - o0;
  float ax = 0.f, ay = 0.f;
  for (int base = 0; base < deg; base += 64) {
    int cnt = min(64, deg - base);
    int cv = (lane < cnt) ? col[o0 + base + lane] : 0;
    int i = 0;
    for (; i + 4 <= cnt; i += 4) {
      int s0 = __shfl(cv, i), s1 = __shfl(cv, i + 1), s2 = __shfl(cv, i + 2), s3 = __shfl(cv, i + 3);
      float2 v0 = *(const float2*)(X + (size_t)s0 * 128 + lane * 2);
      float2 v1 = *(const float2*)(X + (size_t)s1 * 128 + lane * 2);
      float2 v2 = *(const float2*)(X + (size_t)s2 * 128 + lane * 2);
      float2 v3 = *(const float2*)(X + (size_t)s3 * 128 + lane * 2);
      ax += v0.x + v1.x + v2.x + v3.x;
      ay += v0.y + v1.y + v2.y + v3.y;
    }
    for (; i < cnt; ++i) {
      int s0 = __shfl(cv, i);
      float2 v0 = *(const float2*)(X + (size_t)s0 * 128 + lane * 2);
      ax += v0.x;
      ay += v0.y;
    }
  }
  float sc = 1.0f / (float)max(deg, 1);
  float2 r;
  r.x = ax * sc;
  r.y = ay * sc;
  *(float2*)(T + (size_t)wid * 128 + lane * 2) = r;
}

// ---- weight prep: split fp32 W into bf16 hi/lo, fragment-linear -----------
// Bpre layout: [kk 8][half 2][ct 8][lane 64][j 8] bf16 (65536 shorts = 128KB)
// element: col = ct*16 + (lane&15); k = kk*32 + (lane>>4)*8 + j
// Wcat[col][k] = k<128 ? Wl[col][k] : Wr[col][k-128]

__global__ __launch_bounds__(256) void k_wprep(const float* __restrict__ Wl, const float* __restrict__ Wr,
                                               unsigned short* __restrict__ Bpre) {
  int id = blockIdx.x * 256 + threadIdx.x;  // 4096 slots
  if (id >= 4096) return;
  int kk = id >> 9;
  int ct = (id >> 6) & 7;
  int l  = id & 63;
  int colIdx = ct * 16 + (l & 15);
  int k0 = kk * 32 + (l >> 4) * 8;
  const float* W = (k0 < 128) ? Wl : Wr;
  int kb = k0 & 127;
  unsigned short hs[8], ls[8];
#pragma unroll
  for (int j = 0; j < 8; ++j) {
    float v = W[colIdx * 128 + kb + j];
    unsigned short h = f2bf(v);
    hs[j] = h;
    ls[j] = f2bf(v - bf2f(h));
  }
  size_t bh = (size_t)kk * 8192 + ((size_t)ct * 64 + l) * 8;
#pragma unroll
  for (int j = 0; j < 8; ++j) {
    Bpre[bh + j] = hs[j];
    Bpre[bh + 4096 + j] = ls[j];
  }
}

// ---- MFMA fused linear: H = relu([A|X] @ [Wl;Wr].T + b) -------------------
// Block: 256 threads = 4 waves, tile 64 rows x 128 cols, K=256 in 8 steps.
// Wave w owns cols [w*32, w*32+32) (2 col-tiles), all 64 rows (4 row-groups).
// bf16x3: acc += a_hi*b_hi + a_hi*b_lo + a_lo*b_hi  (lo*lo ~4e-5, dropped).
// mode 0: write H. mode 1: pool into gsum (batch sorted).

__global__ __launch_bounds__(256) void k_lin_mfma(
    const float* __restrict__ A, const float* __restrict__ X,
    const unsigned short* __restrict__ Bpre,
    const float* __restrict__ bias, float* __restrict__ OUT,
    const int* __restrict__ batch, float* __restrict__ gsum,
    int N, int mode) {
  __shared__ unsigned short As[4096];  // [half 2][rowgrp 4][lane 64][8]  8KB
  __shared__ unsigned short Bs[8192];  // [half 2][ct 8][lane 64][8]     16KB
  __shared__ float ps[128];

  int tid = threadIdx.x;
  int wv = tid >> 6, ln = tid & 63;
  int rowBase = blockIdx.x * 64;

  // staging identity: thread t handles row t>>2, k-chunk t&3
  int sRow = tid >> 2;
  int sKq = tid & 3;
  int sgr = min(rowBase + sRow, N - 1);
  int sSlot = ((sRow >> 4) * 64 + (sKq << 4) + (sRow & 15)) * 8;  // shorts

  f32x4 acc[4][2];
#pragma unroll
  for (int rg = 0; rg < 4; ++rg) {
    acc[rg][0] = (f32x4){0.f, 0.f, 0.f, 0.f};
    acc[rg][1] = (f32x4){0.f, 0.f, 0.f, 0.f};
  }

  const uint4* BpreV = (const uint4*)Bpre;

  for (int kk = 0; kk < 8; ++kk) {
    const float* S = (kk < 4) ? A : X;
    int kOff = (kk & 3) * 32 + sKq * 8;
    // global loads (issue before barrier; overlap with previous compute)
    float4 p0 = *(const float4*)(S + (size_t)sgr * 128 + kOff);
    float4 p1 = *(const float4*)(S + (size_t)sgr * 128 + kOff + 4);
    uint4 b0 = BpreV[kk * 1024 + tid];
    uint4 b1 = BpreV[kk * 1024 + tid + 256];
    uint4 b2 = BpreV[kk * 1024 + tid + 512];
    uint4 b3 = BpreV[kk * 1024 + tid + 768];

    // convert A chunk to hi/lo bf16
    float fv[8] = {p0.x, p0.y, p0.z, p0.w, p1.x, p1.y, p1.z, p1.w};
    unsigned short hh[8], ll[8];
#pragma unroll
    for (int j = 0; j < 8; ++j) {
      unsigned short h = f2bf(fv[j]);
      hh[j] = h;
      ll[j] = f2bf(fv[j] - bf2f(h));
    }
    uint4 uh, ul;
    uh.x = (unsigned)hh[0] | ((unsigned)hh[1] << 16);
    uh.y = (unsigned)hh[2] | ((unsigned)hh[3] << 16);
    uh.z = (unsigned)hh[4] | ((unsigned)hh[5] << 16);
    uh.w = (unsigned)hh[6] | ((unsigned)hh[7] << 16);
    ul.x = (unsigned)ll[0] | ((unsigned)ll[1] << 16);
    ul.y = (unsigned)ll[2] | ((unsigned)ll[3] << 16);
    ul.z = (unsigned)ll[4] | ((unsigned)ll[5] << 16);
    ul.w = (unsigned)ll[6] | ((unsigned)ll[7] << 16);

    __syncthreads();  // previous iter's reads done
    *(uint4*)(As + sSlot) = uh;
    *(uint4*)(As + 2048 + sSlot) = ul;
    uint4* BsV = (uint4*)Bs;
    BsV[tid] = b0;
    BsV[tid + 256] = b1;
    BsV[tid + 512] = b2;
    BsV[tid + 768] = b3;
    __syncthreads();

    int c0 = wv * 2;
    bf16x8 bh0 = *(bf16x8*)(Bs + ((size_t)c0 * 64 + ln) * 8);
    bf16x8 bl0 = *(bf16x8*)(Bs + 4096 + ((size_t)c0 * 64 + ln) * 8);
    bf16x8 bh1 = *(bf16x8*)(Bs + ((size_t)(c0 + 1) * 64 + ln) * 8);
    bf16x8 bl1 = *(bf16x8*)(Bs + 4096 + ((size_t)(c0 + 1) * 64 + ln) * 8);
#pragma unroll
    for (int rg = 0; rg < 4; ++rg) {
      bf16x8 ah = *(bf16x8*)(As + ((size_t)rg * 64 + ln) * 8);
      bf16x8 al = *(bf16x8*)(As + 2048 + ((size_t)rg * 64 + ln) * 8);
      acc[rg][0] = __builtin_amdgcn_mfma_f32_16x16x32_bf16(ah, bh0, acc[rg][0], 0, 0, 0);
      acc[rg][0] = __builtin_amdgcn_mfma_f32_16x16x32_bf16(ah, bl0, acc[rg][0], 0, 0, 0);
      acc[rg][0] = __builtin_amdgcn_mfma_f32_16x16x32_bf16(al, bh0, acc[rg][0], 0, 0, 0);
      acc[rg][1] = __builtin_amdgcn_mfma_f32_16x16x32_bf16(ah, bh1, acc[rg][1], 0, 0, 0);
      acc[rg][1] = __builtin_amdgcn_mfma_f32_16x16x32_bf16(ah, bl1, acc[rg][1], 0, 0, 0);
      acc[rg][1] = __builtin_amdgcn_mfma_f32_16x16x32_bf16(al, bh1, acc[rg][1], 0, 0, 0);
    }
  }

  // epilogue: bias + relu. C layout: col=lane&15, row=(lane>>4)*4+reg (m89).
  int lcol = ln & 15;
  int rsub = (ln >> 4) * 4;
#pragma unroll
  for (int c = 0; c < 2; ++c) {
    float b = bias[(wv * 2 + c) * 16 + lcol];
#pragma unroll
    for (int rg = 0; rg < 4; ++rg)
#pragma unroll
      for (int r = 0; r < 4; ++r) acc[rg][c][r] = fmaxf(acc[rg][c][r] + b, 0.f);
  }

  if (mode == 0) {
#pragma unroll
    for (int rg = 0; rg < 4; ++rg)
#pragma unroll
      for (int r = 0; r < 4; ++r) {
        int row = rowBase + rg * 16 + rsub + r;
        if (row < N) {
          OUT[(size_t)row * 128 + (wv * 2 + 0) * 16 + lcol] = acc[rg][0][r];
          OUT[(size_t)row * 128 + (wv * 2 + 1) * 16 + lcol] = acc[rg][1][r];
        }
      }
  } else {
    if (tid < 128) ps[tid] = 0.f;
    __syncthreads();
    int lastRow = min(rowBase + 63, N - 1);
    int g0 = batch[rowBase], g1 = batch[lastRow];
    if (g0 == g1) {
#pragma unroll
      for (int c = 0; c < 2; ++c) {
        float s = 0.f;
#pragma unroll
        for (int rg = 0; rg < 4; ++rg)
#pragma unroll
          for (int r = 0; r < 4; ++r) {
            int row = rowBase + rg * 16 + rsub + r;
            if (row < N) s += acc[rg][c][r];
          }
        atomicAdd(&ps[(wv * 2 + c) * 16 + lcol], s);
      }
      __syncthreads();
      if (tid < 128) atomicAdd(&gsum[g0 * 128 + tid], ps[tid]);
    } else {
      // boundary block (rare): per-element atomics
#pragma unroll
      for (int rg = 0; rg < 4; ++rg)
#pragma unroll
        for (int r = 0; r < 4; ++r) {
          int row = rowBase + rg * 16 + rsub + r;
          if (row < N) {
            int g = batch[row];
            atomicAdd(&gsum[g * 128 + (wv * 2 + 0) * 16 + lcol], acc[rg][0][r]);
            atomicAdd(&gsum[g * 128 + (wv * 2 + 1) * 16 + lcol], acc[rg][1][r]);
          }
        }
    }
  }
}

// ---- classifier -----------------------------------------------------------

__global__ __launch_bounds__(128) void k_cls1(const float* __restrict__ gsum, const int* __restrict__ gcnt,
                                              const float* __restrict__ Wc1, const float* __restrict__ bc1,
                                              float* __restrict__ z) {
  int g = blockIdx.x;
  int h = threadIdx.x;
  float inv = 1.0f / (float)max(gcnt[g], 1);
  float s = 0.f;
  for (int f = 0; f < 128; ++f) s += gsum[g * 128 + f] * Wc1[h * 128 + f];
  z[g * 128 + h] = fmaxf(s * inv + bc1[h], 0.f);
}

__global__ __launch_bounds__(128) void k_cls2(const float* __restrict__ z, const float* __restrict__ Wc2,
                                              const float* __restrict__ bc2, float* __restrict__ out) {
  __shared__ float red[128];
  int g = blockIdx.x;
  int t = threadIdx.x;
  red[t] = z[g * 128 + t] * Wc2[t];
  __syncthreads();
  for (int d = 64; d > 0; d >>= 1) {
    if (t < d) red[t] += red[t + d];
    __syncthreads();
  }
  if (t == 0) out[g] = red[0] + bc2[0];
}

// ---------------------------------------------------------------------------

extern "C" void kernel_launch(void* const* d_in, const int* in_sizes, int n_in,
                              void* d_out, int out_size, void* d_ws, size_t ws_size,
                              hipStream_t stream) {
  const float* x   = (const float*)d_in[0];
  const int*   ei  = (const int*)d_in[1];
  const int*   bat = (const int*)d_in[2];
  const float* W1l = (const float*)d_in[3];
  const float* b1l = (const float*)d_in[4];
  const float* W1r = (const float*)d_in[5];
  const float* W2l = (const float*)d_in[6];
  const float* b2l = (const float*)d_in[7];
  const float* W2r = (const float*)d_in[8];
  const float* Wc1 = (const float*)d_in[9];
  const float* bc1 = (const float*)d_in[10];
  const float* Wc2 = (const float*)d_in[11];
  const float* bc2 = (const float*)d_in[12];
  float* out = (float*)d_out;

  int N = in_sizes[0] / 128;
  int E = in_sizes[1] / 2;
  int nScanBlk = (N + 1023) / 1024;

  char* ws = (char*)d_ws;
  size_t o = 0;
  auto alloc = [&](size_t bytes) {
    char* p = ws + o;
    o += (bytes + 255) & ~(size_t)255;
    return p;
  };
  int*   cursor = (int*)alloc((size_t)N * 4);
  int*   off    = (int*)alloc((size_t)(N + 1) * 4);
  int*   col    = (int*)alloc((size_t)E * 4);
  int*   bsum   = (int*)alloc(256 * 4);
  float* T      = (float*)alloc((size_t)N * 128 * 4);
  float* h1     = (float*)alloc((size_t)N * 128 * 4);
  unsigned short* Bpre1 = (unsigned short*)alloc(65536 * 2);  // 128KB
  unsigned short* Bpre2 = (unsigned short*)alloc(65536 * 2);
  float* gsum   = (float*)alloc(64 * 128 * 4 + 64 * 4);
  int*   gcnt   = (int*)(gsum + 64 * 128);
  float* z      = (float*)alloc(64 * 128 * 4);

  hipMemsetAsync(cursor, 0, (size_t)N * 4, stream);
  hipMemsetAsync(gsum, 0, 64 * 128 * 4, stream);

  // weight prep + graph prep
  k_wprep<<<16, 256, 0, stream>>>(W1l, W1r, Bpre1);
  k_wprep<<<16, 256, 0, stream>>>(W2l, W2r, Bpre2);
  k_deg<<<(E + 255) / 256, 256, 0, stream>>>(ei, cursor, E);
  k_gcnt_bs<<<1, 64, 0, stream>>>(bat, gcnt, N, 64);
  k_scan_local<<<nScanBlk, 256, 0, stream>>>(cursor, off, bsum, N);
  k_scan_mid<<<1, 256, 0, stream>>>(bsum, off + N, nScanBlk);
  k_scan_add<<<nScanBlk, 256, 0, stream>>>(off, cursor, bsum, N);
  k_fill<<<(E + 255) / 256, 256, 0, stream>>>(ei, cursor, col, E);

  int nLinBlk = (N + 63) / 64;
  // layer 1
  k_agg<<<(N + 3) / 4, 256, 0, stream>>>(x, off, col, T, N);
  k_lin_mfma<<<nLinBlk, 256, 0, stream>>>(T, x, Bpre1, b1l, h1, bat, gsum, N, 0);
  // layer 2: h2 never materialized — pooled in epilogue
  k_agg<<<(N + 3) / 4, 256, 0, stream>>>(h1, off, col, T, N);
  k_lin_mfma<<<nLinBlk, 256, 0, stream>>>(T, h1, Bpre2, b2l, nullptr, bat, gsum, N, 1);

  // classifier
  k_cls1<<<64, 128, 0, stream>>>(gsum, gcnt, Wc1, bc1, z);
  k_cls2<<<64, 128, 0, stream>>>(z, Wc2, bc2, out);
}

// Round 6
// 211.583 us; speedup vs baseline: 2.5404x; 1.0856x over previous
//
#include <hip/hip_runtime.h>

// ---------------------------------------------------------------------------
// GNN: 2x SAGEConv(mean) + ReLU, global mean pool, 2-layer MLP classifier.
// N=50000 nodes, E=600000 edges, F=H=128, 64 graphs. fp32 in/out.
// R2: hierarchical scan (110us -> ~10us).
// R3: fused global-mean-pool into layer-2 linear epilogue (h2 never hits HBM).
// R4: gcnt via binary search (234us same-address atomics -> ~2us).
// R5: linear -> MFMA bf16x3 (hi*hi+hi*lo+lo*hi), col-partitioned waves.
// R6: gather in bf16 (halves gather bytes 307->154MB logical/layer):
//     x pre-converted once; h1bf written free in lin1 epilogue (aliases xbf).
//     Gather uses ushort8/lane, 4 rows per load inst, shfl_xor reduce.
// ---------------------------------------------------------------------------

typedef __attribute__((ext_vector_type(8))) short bf16x8;
typedef __attribute__((ext_vector_type(8))) unsigned short ushort8;
typedef __attribute__((ext_vector_type(4))) float f32x4;

__device__ inline unsigned short f2bf(float f) {
  unsigned u = __float_as_uint(f);
  u += 0x7fff + ((u >> 16) & 1);  // round-to-nearest-even
  return (unsigned short)(u >> 16);
}
__device__ inline float bf2f(unsigned short h) { return __uint_as_float(((unsigned)h) << 16); }

// ---- CSR build ------------------------------------------------------------

__global__ __launch_bounds__(256) void k_deg(const int* __restrict__ ei, int* __restrict__ cnt, int E) {
  int e = blockIdx.x * 256 + threadIdx.x;
  if (e < E) atomicAdd(&cnt[ei[E + e]], 1);  // dst = ei[E+e]
}

__global__ __launch_bounds__(64) void k_gcnt_bs(const int* __restrict__ batch, int* __restrict__ gcnt,
                                                int N, int G) {
  int g = threadIdx.x;
  if (g >= G) return;
  int lo = 0, hi = N;
  while (lo < hi) { int mid = (lo + hi) >> 1; if (batch[mid] < g) lo = mid + 1; else hi = mid; }
  int a = lo;
  lo = 0; hi = N;
  while (lo < hi) { int mid = (lo + hi) >> 1; if (batch[mid] < g + 1) lo = mid + 1; else hi = mid; }
  gcnt[g] = lo - a;
}

__global__ __launch_bounds__(256) void k_scan_local(const int* __restrict__ cnt, int* __restrict__ off,
                                                    int* __restrict__ bsum, int n) {
  __shared__ int s[256];
  int t = threadIdx.x;
  int base = blockIdx.x * 1024 + t * 4;
  int v0 = 0, v1 = 0, v2 = 0, v3 = 0;
  if (base + 3 < n) {
    int4 q = *(const int4*)(cnt + base);
    v0 = q.x; v1 = q.y; v2 = q.z; v3 = q.w;
  } else {
    if (base + 0 < n) v0 = cnt[base + 0];
    if (base + 1 < n) v1 = cnt[base + 1];
    if (base + 2 < n) v2 = cnt[base + 2];
    if (base + 3 < n) v3 = cnt[base + 3];
  }
  s[t] = v0 + v1 + v2 + v3;
  __syncthreads();
  for (int d = 1; d < 256; d <<= 1) {
    int x = (t >= d) ? s[t - d] : 0;
    __syncthreads();
    s[t] += x;
    __syncthreads();
  }
  int pre = (t == 0) ? 0 : s[t - 1];
  if (t == 255) bsum[blockIdx.x] = s[255];
  int e0 = pre, e1 = e0 + v0, e2 = e1 + v1, e3 = e2 + v2;
  if (base + 3 < n) {
    *(int4*)(off + base) = make_int4(e0, e1, e2, e3);
  } else {
    if (base + 0 < n) off[base + 0] = e0;
    if (base + 1 < n) off[base + 1] = e1;
    if (base + 2 < n) off[base + 2] = e2;
    if (base + 3 < n) off[base + 3] = e3;
  }
}

__global__ __launch_bounds__(256) void k_scan_mid(int* __restrict__ bsum, int* __restrict__ totalOut, int nb) {
  __shared__ int s[256];
  int t = threadIdx.x;
  s[t] = (t < nb) ? bsum[t] : 0;
  __syncthreads();
  for (int d = 1; d < 256; d <<= 1) {
    int x = (t >= d) ? s[t - d] : 0;
    __syncthreads();
    s[t] += x;
    __syncthreads();
  }
  if (t < nb) bsum[t] = (t == 0) ? 0 : s[t - 1];
  if (t == 255) totalOut[0] = s[255];
}

__global__ __launch_bounds__(256) void k_scan_add(int* __restrict__ off, int* __restrict__ cursor,
                                                  const int* __restrict__ bsum, int n) {
  int base = blockIdx.x * 1024 + threadIdx.x * 4;
  int b = bsum[blockIdx.x];
  if (base + 3 < n) {
    int4 q = *(const int4*)(off + base);
    q.x += b; q.y += b; q.z += b; q.w += b;
    *(int4*)(off + base) = q;
    *(int4*)(cursor + base) = q;
  } else {
    for (int k = 0; k < 4; ++k)
      if (base + k < n) {
        int v = off[base + k] + b;
        off[base + k] = v;
        cursor[base + k] = v;
      }
  }
}

__global__ __launch_bounds__(256) void k_fill(const int* __restrict__ ei, int* __restrict__ cursor,
                                              int* __restrict__ col, int E) {
  int e = blockIdx.x * 256 + threadIdx.x;
  if (e < E) {
    int d = ei[E + e];
    int p = atomicAdd(&cursor[d], 1);
    col[p] = ei[e];          // src
  }
}

// ---- fp32 -> bf16 convert (for gather source) -----------------------------

__global__ __launch_bounds__(256) void k_tobf(const float* __restrict__ x,
                                              unsigned short* __restrict__ xbf, int total) {
  int i = (blockIdx.x * 256 + threadIdx.x) * 4;
  if (i + 3 < total) {
    float4 v = *(const float4*)(x + i);
    ushort4 p;
    p.x = f2bf(v.x); p.y = f2bf(v.y); p.z = f2bf(v.z); p.w = f2bf(v.w);
    *(ushort4*)(xbf + i) = p;
  } else {
    for (int k = 0; k < 4 && i + k < total; ++k) xbf[i + k] = f2bf(x[i + k]);
  }
}

// ---- mean aggregation (bf16 source): T[i,:] = mean_{j in N(i)} X[j,:] -----
// One wave per node. Lane l: row-group rs=l>>4 (4 rows per load inst),
// feature slice fs=l&15 (8 features, ushort8=16B). Unroll 4 -> 16 rows
// in flight per wave. Cross row-group reduce via shfl_xor(16,32).

__global__ __launch_bounds__(256) void k_agg_bf(const unsigned short* __restrict__ Xbf,
                                                const int* __restrict__ off, const int* __restrict__ col,
                                                float* __restrict__ T, int N) {
  int wid = (blockIdx.x * 256 + threadIdx.x) >> 6;
  int ln = threadIdx.x & 63;
  if (wid >= N) return;
  int o0 = off[wid], o1 = off[wid + 1];
  int deg = o1 - o0;
  int rs = ln >> 4, fs = ln & 15;
  float acc[8];
#pragma unroll
  for (int j = 0; j < 8; ++j) acc[j] = 0.f;

  for (int base = 0; base < deg; base += 16) {
#pragma unroll
    for (int u = 0; u < 4; ++u) {
      int n = base + u * 4 + rs;
      if (n < deg) {
        int idx = col[o0 + n];
        ushort8 q = *(const ushort8*)(Xbf + (size_t)idx * 128 + fs * 8);
#pragma unroll
        for (int j = 0; j < 8; ++j) acc[j] += bf2f(q[j]);
      }
    }
  }
#pragma unroll
  for (int j = 0; j < 8; ++j) {
    acc[j] += __shfl_xor(acc[j], 16);
    acc[j] += __shfl_xor(acc[j], 32);
  }
  if (rs == 0) {
    float sc = 1.0f / (float)max(deg, 1);
    float4 r0 = {acc[0] * sc, acc[1] * sc, acc[2] * sc, acc[3] * sc};
    float4 r1 = {acc[4] * sc, acc[5] * sc, acc[6] * sc, acc[7] * sc};
    *(float4*)(T + (size_t)wid * 128 + fs * 8) = r0;
    *(float4*)(T + (size_t)wid * 128 + fs * 8 + 4) = r1;
  }
}

// ---- weight prep: split fp32 W into bf16 hi/lo, fragment-linear -----------
// Bpre layout: [kk 8][half 2][ct 8][lane 64][j 8] bf16 (65536 shorts = 128KB)
// element: col = ct*16 + (lane&15); k = kk*32 + (lane>>4)*8 + j

__global__ __launch_bounds__(256) void k_wprep(const float* __restrict__ Wl, const float* __restrict__ Wr,
                                               unsigned short* __restrict__ Bpre) {
  int id = blockIdx.x * 256 + threadIdx.x;  // 4096 slots
  if (id >= 4096) return;
  int kk = id >> 9;
  int ct = (id >> 6) & 7;
  int l  = id & 63;
  int colIdx = ct * 16 + (l & 15);
  int k0 = kk * 32 + (l >> 4) * 8;
  const float* W = (k0 < 128) ? Wl : Wr;
  int kb = k0 & 127;
  unsigned short hs[8], ls[8];
#pragma unroll
  for (int j = 0; j < 8; ++j) {
    float v = W[colIdx * 128 + kb + j];
    unsigned short h = f2bf(v);
    hs[j] = h;
    ls[j] = f2bf(v - bf2f(h));
  }
  size_t bh = (size_t)kk * 8192 + ((size_t)ct * 64 + l) * 8;
#pragma unroll
  for (int j = 0; j < 8; ++j) {
    Bpre[bh + j] = hs[j];
    Bpre[bh + 4096 + j] = ls[j];
  }
}

// ---- MFMA fused linear: H = relu([A|X] @ [Wl;Wr].T + b) -------------------
// mode 0: write H fp32 (+bf16 copy for next layer's gather).
// mode 1: pool into gsum (batch sorted).

__global__ __launch_bounds__(256) void k_lin_mfma(
    const float* __restrict__ A, const float* __restrict__ X,
    const unsigned short* __restrict__ Bpre,
    const float* __restrict__ bias, float* __restrict__ OUT,
    unsigned short* __restrict__ OUTbf,
    const int* __restrict__ batch, float* __restrict__ gsum,
    int N, int mode) {
  __shared__ unsigned short As[4096];  // [half 2][rowgrp 4][lane 64][8]  8KB
  __shared__ unsigned short Bs[8192];  // [half 2][ct 8][lane 64][8]     16KB
  __shared__ float ps[128];

  int tid = threadIdx.x;
  int wv = tid >> 6, ln = tid & 63;
  int rowBase = blockIdx.x * 64;

  int sRow = tid >> 2;
  int sKq = tid & 3;
  int sgr = min(rowBase + sRow, N - 1);
  int sSlot = ((sRow >> 4) * 64 + (sKq << 4) + (sRow & 15)) * 8;  // shorts

  f32x4 acc[4][2];
#pragma unroll
  for (int rg = 0; rg < 4; ++rg) {
    acc[rg][0] = (f32x4){0.f, 0.f, 0.f, 0.f};
    acc[rg][1] = (f32x4){0.f, 0.f, 0.f, 0.f};
  }

  const uint4* BpreV = (const uint4*)Bpre;

  for (int kk = 0; kk < 8; ++kk) {
    const float* S = (kk < 4) ? A : X;
    int kOff = (kk & 3) * 32 + sKq * 8;
    float4 p0 = *(const float4*)(S + (size_t)sgr * 128 + kOff);
    float4 p1 = *(const float4*)(S + (size_t)sgr * 128 + kOff + 4);
    uint4 b0 = BpreV[kk * 1024 + tid];
    uint4 b1 = BpreV[kk * 1024 + tid + 256];
    uint4 b2 = BpreV[kk * 1024 + tid + 512];
    uint4 b3 = BpreV[kk * 1024 + tid + 768];

    float fv[8] = {p0.x, p0.y, p0.z, p0.w, p1.x, p1.y, p1.z, p1.w};
    unsigned short hh[8], ll[8];
#pragma unroll
    for (int j = 0; j < 8; ++j) {
      unsigned short h = f2bf(fv[j]);
      hh[j] = h;
      ll[j] = f2bf(fv[j] - bf2f(h));
    }
    uint4 uh, ul;
    uh.x = (unsigned)hh[0] | ((unsigned)hh[1] << 16);
    uh.y = (unsigned)hh[2] | ((unsigned)hh[3] << 16);
    uh.z = (unsigned)hh[4] | ((unsigned)hh[5] << 16);
    uh.w = (unsigned)hh[6] | ((unsigned)hh[7] << 16);
    ul.x = (unsigned)ll[0] | ((unsigned)ll[1] << 16);
    ul.y = (unsigned)ll[2] | ((unsigned)ll[3] << 16);
    ul.z = (unsigned)ll[4] | ((unsigned)ll[5] << 16);
    ul.w = (unsigned)ll[6] | ((unsigned)ll[7] << 16);

    __syncthreads();
    *(uint4*)(As + sSlot) = uh;
    *(uint4*)(As + 2048 + sSlot) = ul;
    uint4* BsV = (uint4*)Bs;
    BsV[tid] = b0;
    BsV[tid + 256] = b1;
    BsV[tid + 512] = b2;
    BsV[tid + 768] = b3;
    __syncthreads();

    int c0 = wv * 2;
    bf16x8 bh0 = *(bf16x8*)(Bs + ((size_t)c0 * 64 + ln) * 8);
    bf16x8 bl0 = *(bf16x8*)(Bs + 4096 + ((size_t)c0 * 64 + ln) * 8);
    bf16x8 bh1 = *(bf16x8*)(Bs + ((size_t)(c0 + 1) * 64 + ln) * 8);
    bf16x8 bl1 = *(bf16x8*)(Bs + 4096 + ((size_t)(c0 + 1) * 64 + ln) * 8);
#pragma unroll
    for (int rg = 0; rg < 4; ++rg) {
      bf16x8 ah = *(bf16x8*)(As + ((size_t)rg * 64 + ln) * 8);
      bf16x8 al = *(bf16x8*)(As + 2048 + ((size_t)rg * 64 + ln) * 8);
      acc[rg][0] = __builtin_amdgcn_mfma_f32_16x16x32_bf16(ah, bh0, acc[rg][0], 0, 0, 0);
      acc[rg][0] = __builtin_amdgcn_mfma_f32_16x16x32_bf16(ah, bl0, acc[rg][0], 0, 0, 0);
      acc[rg][0] = __builtin_amdgcn_mfma_f32_16x16x32_bf16(al, bh0, acc[rg][0], 0, 0, 0);
      acc[rg][1] = __builtin_amdgcn_mfma_f32_16x16x32_bf16(ah, bh1, acc[rg][1], 0, 0, 0);
      acc[rg][1] = __builtin_amdgcn_mfma_f32_16x16x32_bf16(ah, bl1, acc[rg][1], 0, 0, 0);
      acc[rg][1] = __builtin_amdgcn_mfma_f32_16x16x32_bf16(al, bh1, acc[rg][1], 0, 0, 0);
    }
  }

  // epilogue: bias + relu. C layout: col=lane&15, row=(lane>>4)*4+reg (m89).
  int lcol = ln & 15;
  int rsub = (ln >> 4) * 4;
#pragma unroll
  for (int c = 0; c < 2; ++c) {
    float b = bias[(wv * 2 + c) * 16 + lcol];
#pragma unroll
    for (int rg = 0; rg < 4; ++rg)
#pragma unroll
      for (int r = 0; r < 4; ++r) acc[rg][c][r] = fmaxf(acc[rg][c][r] + b, 0.f);
  }

  if (mode == 0) {
#pragma unroll
    for (int rg = 0; rg < 4; ++rg)
#pragma unroll
      for (int r = 0; r < 4; ++r) {
        int row = rowBase + rg * 16 + rsub + r;
        if (row < N) {
          int c0i = (wv * 2 + 0) * 16 + lcol;
          int c1i = (wv * 2 + 1) * 16 + lcol;
          OUT[(size_t)row * 128 + c0i] = acc[rg][0][r];
          OUT[(size_t)row * 128 + c1i] = acc[rg][1][r];
          OUTbf[(size_t)row * 128 + c0i] = f2bf(acc[rg][0][r]);
          OUTbf[(size_t)row * 128 + c1i] = f2bf(acc[rg][1][r]);
        }
      }
  } else {
    if (tid < 128) ps[tid] = 0.f;
    __syncthreads();
    int lastRow = min(rowBase + 63, N - 1);
    int g0 = batch[rowBase], g1 = batch[lastRow];
    if (g0 == g1) {
#pragma unroll
      for (int c = 0; c < 2; ++c) {
        float s = 0.f;
#pragma unroll
        for (int rg = 0; rg < 4; ++rg)
#pragma unroll
          for (int r = 0; r < 4; ++r) {
            int row = rowBase + rg * 16 + rsub + r;
            if (row < N) s += acc[rg][c][r];
          }
        atomicAdd(&ps[(wv * 2 + c) * 16 + lcol], s);
      }
      __syncthreads();
      if (tid < 128) atomicAdd(&gsum[g0 * 128 + tid], ps[tid]);
    } else {
#pragma unroll
      for (int rg = 0; rg < 4; ++rg)
#pragma unroll
        for (int r = 0; r < 4; ++r) {
          int row = rowBase + rg * 16 + rsub + r;
          if (row < N) {
            int g = batch[row];
            atomicAdd(&gsum[g * 128 + (wv * 2 + 0) * 16 + lcol], acc[rg][0][r]);
            atomicAdd(&gsum[g * 128 + (wv * 2 + 1) * 16 + lcol], acc[rg][1][r]);
          }
        }
    }
  }
}

// ---- classifier -----------------------------------------------------------

__global__ __launch_bounds__(128) void k_cls1(const float* __restrict__ gsum, const int* __restrict__ gcnt,
                                              const float* __restrict__ Wc1, const float* __restrict__ bc1,
                                              float* __restrict__ z) {
  int g = blockIdx.x;
  int h = threadIdx.x;
  float inv = 1.0f / (float)max(gcnt[g], 1);
  float s = 0.f;
  for (int f = 0; f < 128; ++f) s += gsum[g * 128 + f] * Wc1[h * 128 + f];
  z[g * 128 + h] = fmaxf(s * inv + bc1[h], 0.f);
}

__global__ __launch_bounds__(128) void k_cls2(const float* __restrict__ z, const float* __restrict__ Wc2,
                                              const float* __restrict__ bc2, float* __restrict__ out) {
  __shared__ float red[128];
  int g = blockIdx.x;
  int t = threadIdx.x;
  red[t] = z[g * 128 + t] * Wc2[t];
  __syncthreads();
  for (int d = 64; d > 0; d >>= 1) {
    if (t < d) red[t] += red[t + d];
    __syncthreads();
  }
  if (t == 0) out[g] = red[0] + bc2[0];
}

// ---------------------------------------------------------------------------

extern "C" void kernel_launch(void* const* d_in, const int* in_sizes, int n_in,
                              void* d_out, int out_size, void* d_ws, size_t ws_size,
                              hipStream_t stream) {
  const float* x   = (const float*)d_in[0];
  const int*   ei  = (const int*)d_in[1];
  const int*   bat = (const int*)d_in[2];
  const float* W1l = (const float*)d_in[3];
  const float* b1l = (const float*)d_in[4];
  const float* W1r = (const float*)d_in[5];
  const float* W2l = (const float*)d_in[6];
  const float* b2l = (const float*)d_in[7];
  const float* W2r = (const float*)d_in[8];
  const float* Wc1 = (const float*)d_in[9];
  const float* bc1 = (const float*)d_in[10];
  const float* Wc2 = (const float*)d_in[11];
  const float* bc2 = (const float*)d_in[12];
  float* out = (float*)d_out;

  int N = in_sizes[0] / 128;
  int E = in_sizes[1] / 2;
  int nScanBlk = (N + 1023) / 1024;

  char* ws = (char*)d_ws;
  size_t o = 0;
  auto alloc = [&](size_t bytes) {
    char* p = ws + o;
    o += (bytes + 255) & ~(size_t)255;
    return p;
  };
  int*   cursor = (int*)alloc((size_t)N * 4);
  int*   off    = (int*)alloc((size_t)(N + 1) * 4);
  int*   col    = (int*)alloc((size_t)E * 4);
  int*   bsum   = (int*)alloc(256 * 4);
  float* T      = (float*)alloc((size_t)N * 128 * 4);
  float* h1     = (float*)alloc((size_t)N * 128 * 4);
  unsigned short* xbf = (unsigned short*)alloc((size_t)N * 128 * 2);  // reused as h1bf
  unsigned short* Bpre1 = (unsigned short*)alloc(65536 * 2);
  unsigned short* Bpre2 = (unsigned short*)alloc(65536 * 2);
  float* gsum   = (float*)alloc(64 * 128 * 4 + 64 * 4);
  int*   gcnt   = (int*)(gsum + 64 * 128);
  float* z      = (float*)alloc(64 * 128 * 4);

  hipMemsetAsync(cursor, 0, (size_t)N * 4, stream);
  hipMemsetAsync(gsum, 0, 64 * 128 * 4, stream);

  // prep
  k_tobf<<<(N * 128 / 4 + 255) / 256, 256, 0, stream>>>(x, xbf, N * 128);
  k_wprep<<<16, 256, 0, stream>>>(W1l, W1r, Bpre1);
  k_wprep<<<16, 256, 0, stream>>>(W2l, W2r, Bpre2);
  k_deg<<<(E + 255) / 256, 256, 0, stream>>>(ei, cursor, E);
  k_gcnt_bs<<<1, 64, 0, stream>>>(bat, gcnt, N, 64);
  k_scan_local<<<nScanBlk, 256, 0, stream>>>(cursor, off, bsum, N);
  k_scan_mid<<<1, 256, 0, stream>>>(bsum, off + N, nScanBlk);
  k_scan_add<<<nScanBlk, 256, 0, stream>>>(off, cursor, bsum, N);
  k_fill<<<(E + 255) / 256, 256, 0, stream>>>(ei, cursor, col, E);

  int nLinBlk = (N + 63) / 64;
  // layer 1 (gather bf16 x; lin writes h1 fp32 + h1bf into xbf buffer)
  k_agg_bf<<<(N + 3) / 4, 256, 0, stream>>>(xbf, off, col, T, N);
  k_lin_mfma<<<nLinBlk, 256, 0, stream>>>(T, x, Bpre1, b1l, h1, xbf, bat, gsum, N, 0);
  // layer 2 (gather bf16 h1; pooled in epilogue, h2 never materialized)
  k_agg_bf<<<(N + 3) / 4, 256, 0, stream>>>(xbf, off, col, T, N);
  k_lin_mfma<<<nLinBlk, 256, 0, stream>>>(T, h1, Bpre2, b2l, nullptr, nullptr, bat, gsum, N, 1);

  // classifier
  k_cls1<<<64, 128, 0, stream>>>(gsum, gcnt, Wc1, bc1, z);
  k_cls2<<<64, 128, 0, stream>>>(z, Wc2, bc2, out);
}

// Round 7
// 201.371 us; speedup vs baseline: 2.6692x; 1.0507x over previous
//
#include <hip/hip_runtime.h>

// ---------------------------------------------------------------------------
// GNN: 2x SAGEConv(mean) + ReLU, global mean pool, 2-layer MLP classifier.
// N=50000 nodes, E=600000 edges, F=H=128, 64 graphs. fp32 in/out.
// R2: hierarchical scan. R3: pool fused into layer-2 linear epilogue.
// R4: gcnt via binary search. R5: linear -> MFMA bf16x3. R6: bf16 gather.
// R7: CSR build via two-level counting sort (LDS atomics only). The old
//     k_deg/k_fill global-atomic build cost ~75us because every scattered
//     4B write/atomic became a 64B HBM line (WRITE_SIZE 37MB for 2.4MB col).
// ---------------------------------------------------------------------------

typedef __attribute__((ext_vector_type(8))) short bf16x8;
typedef __attribute__((ext_vector_type(8))) unsigned short ushort8;
typedef __attribute__((ext_vector_type(4))) float f32x4;

#define HBLK 4096  // edges per block in the bucket passes

__device__ inline unsigned short f2bf(float f) {
  unsigned u = __float_as_uint(f);
  u += 0x7fff + ((u >> 16) & 1);  // round-to-nearest-even
  return (unsigned short)(u >> 16);
}
__device__ inline float bf2f(unsigned short h) { return __uint_as_float(((unsigned)h) << 16); }

// ---- CSR build: two-level counting sort (no global atomics) ---------------
// Bucket key = dst>>8 (256 buckets covers N<=65536).

// pass 1a: per-block histogram over 256 buckets
__global__ __launch_bounds__(256) void k_hist(const int* __restrict__ ei, int* __restrict__ bhist, int E) {
  __shared__ int h[256];
  int tid = threadIdx.x;
  h[tid] = 0;
  __syncthreads();
  int base = blockIdx.x * HBLK;
  int end = min(base + HBLK, E);
  for (int e = base + tid; e < end; e += 256) {
    int d = ei[E + e];
    atomicAdd(&h[d >> 8], 1);
  }
  __syncthreads();
  bhist[blockIdx.x * 256 + tid] = h[tid];
}

// pass 1b: column-scan bhist -> per-block per-bucket base cursors; bucket bases
__global__ __launch_bounds__(256) void k_bscan(int* __restrict__ bhist, int* __restrict__ bukbase,
                                               int nblk, int E) {
  __shared__ int s[256];
  int t = threadIdx.x;
  int sum = 0;
  for (int b = 0; b < nblk; ++b) sum += bhist[b * 256 + t];
  s[t] = sum;
  __syncthreads();
  for (int d = 1; d < 256; d <<= 1) {
    int v = (t >= d) ? s[t - d] : 0;
    __syncthreads();
    s[t] += v;
    __syncthreads();
  }
  int basev = (t == 0) ? 0 : s[t - 1];
  bukbase[t] = basev;
  if (t == 255) bukbase[256] = s[255];  // == E
  int run = basev;
  for (int b = 0; b < nblk; ++b) {
    int c = bhist[b * 256 + t];
    bhist[b * 256 + t] = run;
    run += c;
  }
}

// pass 1c: scatter edges into bucket order, packed (dstLow8<<24 | src)
__global__ __launch_bounds__(256) void k_scat(const int* __restrict__ ei, const int* __restrict__ bhist,
                                              unsigned* __restrict__ ebuk, int E) {
  __shared__ int cur[256];
  int tid = threadIdx.x;
  cur[tid] = bhist[blockIdx.x * 256 + tid];
  __syncthreads();
  int base = blockIdx.x * HBLK;
  int end = min(base + HBLK, E);
  for (int e = base + tid; e < end; e += 256) {
    int d = ei[E + e];
    int srcv = ei[e];
    int p = atomicAdd(&cur[d >> 8], 1);
    ebuk[p] = ((unsigned)(d & 255) << 24) | (unsigned)srcv;
  }
}

// pass 2: per-bucket local counting sort -> off (coalesced) + col
__global__ __launch_bounds__(256) void k_bucket(const unsigned* __restrict__ ebuk,
                                                const int* __restrict__ bukbase,
                                                int* __restrict__ off, int* __restrict__ colv,
                                                int N, int E) {
  __shared__ int h[256];
  __shared__ int cur[256];
  int tid = threadIdx.x;
  int buk = blockIdx.x;
  int b0 = bukbase[buk], b1 = bukbase[buk + 1];
  h[tid] = 0;
  __syncthreads();
  for (int i = b0 + tid; i < b1; i += 256) atomicAdd(&h[ebuk[i] >> 24], 1);
  __syncthreads();
  int my = h[tid];
  int s = my;
  // inclusive scan in LDS (reuse h)
  __shared__ int sc[256];
  sc[tid] = s;
  __syncthreads();
  for (int d = 1; d < 256; d <<= 1) {
    int v = (tid >= d) ? sc[tid - d] : 0;
    __syncthreads();
    sc[tid] += v;
    __syncthreads();
  }
  int excl = sc[tid] - my;
  cur[tid] = excl;
  int node = buk * 256 + tid;
  if (node < N) off[node] = b0 + excl;
  if (buk == gridDim.x - 1 && tid == 0) off[N] = E;
  __syncthreads();
  for (int i = b0 + tid; i < b1; i += 256) {
    unsigned v = ebuk[i];
    int p = atomicAdd(&cur[v >> 24], 1);
    colv[b0 + p] = (int)(v & 0xFFFFFFu);
  }
}

// ---- gcnt via binary search on sorted batch -------------------------------

__global__ __launch_bounds__(64) void k_gcnt_bs(const int* __restrict__ batch, int* __restrict__ gcnt,
                                                int N, int G) {
  int g = threadIdx.x;
  if (g >= G) return;
  int lo = 0, hi = N;
  while (lo < hi) { int mid = (lo + hi) >> 1; if (batch[mid] < g) lo = mid + 1; else hi = mid; }
  int a = lo;
  lo = 0; hi = N;
  while (lo < hi) { int mid = (lo + hi) >> 1; if (batch[mid] < g + 1) lo = mid + 1; else hi = mid; }
  gcnt[g] = lo - a;
}

// ---- fp32 -> bf16 convert (gather source) ---------------------------------

__global__ __launch_bounds__(256) void k_tobf(const float* __restrict__ x,
                                              unsigned short* __restrict__ xbf, int total) {
  int i = (blockIdx.x * 256 + threadIdx.x) * 4;
  if (i + 3 < total) {
    float4 v = *(const float4*)(x + i);
    ushort4 p;
    p.x = f2bf(v.x); p.y = f2bf(v.y); p.z = f2bf(v.z); p.w = f2bf(v.w);
    *(ushort4*)(xbf + i) = p;
  } else {
    for (int k = 0; k < 4 && i + k < total; ++k) xbf[i + k] = f2bf(x[i + k]);
  }
}

// ---- mean aggregation (bf16 source) ---------------------------------------

__global__ __launch_bounds__(256) void k_agg_bf(const unsigned short* __restrict__ Xbf,
                                                const int* __restrict__ off, const int* __restrict__ col,
                                                float* __restrict__ T, int N) {
  int wid = (blockIdx.x * 256 + threadIdx.x) >> 6;
  int ln = threadIdx.x & 63;
  if (wid >= N) return;
  int o0 = off[wid], o1 = off[wid + 1];
  int deg = o1 - o0;
  int rs = ln >> 4, fs = ln & 15;
  float acc[8];
#pragma unroll
  for (int j = 0; j < 8; ++j) acc[j] = 0.f;

  for (int base = 0; base < deg; base += 16) {
#pragma unroll
    for (int u = 0; u < 4; ++u) {
      int n = base + u * 4 + rs;
      if (n < deg) {
        int idx = col[o0 + n];
        ushort8 q = *(const ushort8*)(Xbf + (size_t)idx * 128 + fs * 8);
#pragma unroll
        for (int j = 0; j < 8; ++j) acc[j] += bf2f(q[j]);
      }
    }
  }
#pragma unroll
  for (int j = 0; j < 8; ++j) {
    acc[j] += __shfl_xor(acc[j], 16);
    acc[j] += __shfl_xor(acc[j], 32);
  }
  if (rs == 0) {
    float sc = 1.0f / (float)max(deg, 1);
    float4 r0 = {acc[0] * sc, acc[1] * sc, acc[2] * sc, acc[3] * sc};
    float4 r1 = {acc[4] * sc, acc[5] * sc, acc[6] * sc, acc[7] * sc};
    *(float4*)(T + (size_t)wid * 128 + fs * 8) = r0;
    *(float4*)(T + (size_t)wid * 128 + fs * 8 + 4) = r1;
  }
}

// ---- weight prep: split fp32 W into bf16 hi/lo, fragment-linear -----------

__global__ __launch_bounds__(256) void k_wprep(const float* __restrict__ Wl, const float* __restrict__ Wr,
                                               unsigned short* __restrict__ Bpre) {
  int id = blockIdx.x * 256 + threadIdx.x;  // 4096 slots
  if (id >= 4096) return;
  int kk = id >> 9;
  int ct = (id >> 6) & 7;
  int l  = id & 63;
  int colIdx = ct * 16 + (l & 15);
  int k0 = kk * 32 + (l >> 4) * 8;
  const float* W = (k0 < 128) ? Wl : Wr;
  int kb = k0 & 127;
  unsigned short hs[8], ls[8];
#pragma unroll
  for (int j = 0; j < 8; ++j) {
    float v = W[colIdx * 128 + kb + j];
    unsigned short h = f2bf(v);
    hs[j] = h;
    ls[j] = f2bf(v - bf2f(h));
  }
  size_t bh = (size_t)kk * 8192 + ((size_t)ct * 64 + l) * 8;
#pragma unroll
  for (int j = 0; j < 8; ++j) {
    Bpre[bh + j] = hs[j];
    Bpre[bh + 4096 + j] = ls[j];
  }
}

// ---- MFMA fused linear: H = relu([A|X] @ [Wl;Wr].T + b) -------------------

__global__ __launch_bounds__(256) void k_lin_mfma(
    const float* __restrict__ A, const float* __restrict__ X,
    const unsigned short* __restrict__ Bpre,
    const float* __restrict__ bias, float* __restrict__ OUT,
    unsigned short* __restrict__ OUTbf,
    const int* __restrict__ batch, float* __restrict__ gsum,
    int N, int mode) {
  __shared__ unsigned short As[4096];  // [half 2][rowgrp 4][lane 64][8]  8KB
  __shared__ unsigned short Bs[8192];  // [half 2][ct 8][lane 64][8]     16KB
  __shared__ float ps[128];

  int tid = threadIdx.x;
  int wv = tid >> 6, ln = tid & 63;
  int rowBase = blockIdx.x * 64;

  int sRow = tid >> 2;
  int sKq = tid & 3;
  int sgr = min(rowBase + sRow, N - 1);
  int sSlot = ((sRow >> 4) * 64 + (sKq << 4) + (sRow & 15)) * 8;  // shorts

  f32x4 acc[4][2];
#pragma unroll
  for (int rg = 0; rg < 4; ++rg) {
    acc[rg][0] = (f32x4){0.f, 0.f, 0.f, 0.f};
    acc[rg][1] = (f32x4){0.f, 0.f, 0.f, 0.f};
  }

  const uint4* BpreV = (const uint4*)Bpre;

  for (int kk = 0; kk < 8; ++kk) {
    const float* S = (kk < 4) ? A : X;
    int kOff = (kk & 3) * 32 + sKq * 8;
    float4 p0 = *(const float4*)(S + (size_t)sgr * 128 + kOff);
    float4 p1 = *(const float4*)(S + (size_t)sgr * 128 + kOff + 4);
    uint4 b0 = BpreV[kk * 1024 + tid];
    uint4 b1 = BpreV[kk * 1024 + tid + 256];
    uint4 b2 = BpreV[kk * 1024 + tid + 512];
    uint4 b3 = BpreV[kk * 1024 + tid + 768];

    float fv[8] = {p0.x, p0.y, p0.z, p0.w, p1.x, p1.y, p1.z, p1.w};
    unsigned short hh[8], ll[8];
#pragma unroll
    for (int j = 0; j < 8; ++j) {
      unsigned short h = f2bf(fv[j]);
      hh[j] = h;
      ll[j] = f2bf(fv[j] - bf2f(h));
    }
    uint4 uh, ul;
    uh.x = (unsigned)hh[0] | ((unsigned)hh[1] << 16);
    uh.y = (unsigned)hh[2] | ((unsigned)hh[3] << 16);
    uh.z = (unsigned)hh[4] | ((unsigned)hh[5] << 16);
    uh.w = (unsigned)hh[6] | ((unsigned)hh[7] << 16);
    ul.x = (unsigned)ll[0] | ((unsigned)ll[1] << 16);
    ul.y = (unsigned)ll[2] | ((unsigned)ll[3] << 16);
    ul.z = (unsigned)ll[4] | ((unsigned)ll[5] << 16);
    ul.w = (unsigned)ll[6] | ((unsigned)ll[7] << 16);

    __syncthreads();
    *(uint4*)(As + sSlot) = uh;
    *(uint4*)(As + 2048 + sSlot) = ul;
    uint4* BsV = (uint4*)Bs;
    BsV[tid] = b0;
    BsV[tid + 256] = b1;
    BsV[tid + 512] = b2;
    BsV[tid + 768] = b3;
    __syncthreads();

    int c0 = wv * 2;
    bf16x8 bh0 = *(bf16x8*)(Bs + ((size_t)c0 * 64 + ln) * 8);
    bf16x8 bl0 = *(bf16x8*)(Bs + 4096 + ((size_t)c0 * 64 + ln) * 8);
    bf16x8 bh1 = *(bf16x8*)(Bs + ((size_t)(c0 + 1) * 64 + ln) * 8);
    bf16x8 bl1 = *(bf16x8*)(Bs + 4096 + ((size_t)(c0 + 1) * 64 + ln) * 8);
#pragma unroll
    for (int rg = 0; rg < 4; ++rg) {
      bf16x8 ah = *(bf16x8*)(As + ((size_t)rg * 64 + ln) * 8);
      bf16x8 al = *(bf16x8*)(As + 2048 + ((size_t)rg * 64 + ln) * 8);
      acc[rg][0] = __builtin_amdgcn_mfma_f32_16x16x32_bf16(ah, bh0, acc[rg][0], 0, 0, 0);
      acc[rg][0] = __builtin_amdgcn_mfma_f32_16x16x32_bf16(ah, bl0, acc[rg][0], 0, 0, 0);
      acc[rg][0] = __builtin_amdgcn_mfma_f32_16x16x32_bf16(al, bh0, acc[rg][0], 0, 0, 0);
      acc[rg][1] = __builtin_amdgcn_mfma_f32_16x16x32_bf16(ah, bh1, acc[rg][1], 0, 0, 0);
      acc[rg][1] = __builtin_amdgcn_mfma_f32_16x16x32_bf16(ah, bl1, acc[rg][1], 0, 0, 0);
      acc[rg][1] = __builtin_amdgcn_mfma_f32_16x16x32_bf16(al, bh1, acc[rg][1], 0, 0, 0);
    }
  }

  // epilogue: bias + relu. C layout: col=lane&15, row=(lane>>4)*4+reg (m89).
  int lcol = ln & 15;
  int rsub = (ln >> 4) * 4;
#pragma unroll
  for (int c = 0; c < 2; ++c) {
    float b = bias[(wv * 2 + c) * 16 + lcol];
#pragma unroll
    for (int rg = 0; rg < 4; ++rg)
#pragma unroll
      for (int r = 0; r < 4; ++r) acc[rg][c][r] = fmaxf(acc[rg][c][r] + b, 0.f);
  }

  if (mode == 0) {
#pragma unroll
    for (int rg = 0; rg < 4; ++rg)
#pragma unroll
      for (int r = 0; r < 4; ++r) {
        int row = rowBase + rg * 16 + rsub + r;
        if (row < N) {
          int c0i = (wv * 2 + 0) * 16 + lcol;
          int c1i = (wv * 2 + 1) * 16 + lcol;
          OUT[(size_t)row * 128 + c0i] = acc[rg][0][r];
          OUT[(size_t)row * 128 + c1i] = acc[rg][1][r];
          OUTbf[(size_t)row * 128 + c0i] = f2bf(acc[rg][0][r]);
          OUTbf[(size_t)row * 128 + c1i] = f2bf(acc[rg][1][r]);
        }
      }
  } else {
    if (tid < 128) ps[tid] = 0.f;
    __syncthreads();
    int lastRow = min(rowBase + 63, N - 1);
    int g0 = batch[rowBase], g1 = batch[lastRow];
    if (g0 == g1) {
#pragma unroll
      for (int c = 0; c < 2; ++c) {
        float s = 0.f;
#pragma unroll
        for (int rg = 0; rg < 4; ++rg)
#pragma unroll
          for (int r = 0; r < 4; ++r) {
            int row = rowBase + rg * 16 + rsub + r;
            if (row < N) s += acc[rg][c][r];
          }
        atomicAdd(&ps[(wv * 2 + c) * 16 + lcol], s);
      }
      __syncthreads();
      if (tid < 128) atomicAdd(&gsum[g0 * 128 + tid], ps[tid]);
    } else {
#pragma unroll
      for (int rg = 0; rg < 4; ++rg)
#pragma unroll
        for (int r = 0; r < 4; ++r) {
          int row = rowBase + rg * 16 + rsub + r;
          if (row < N) {
            int g = batch[row];
            atomicAdd(&gsum[g * 128 + (wv * 2 + 0) * 16 + lcol], acc[rg][0][r]);
            atomicAdd(&gsum[g * 128 + (wv * 2 + 1) * 16 + lcol], acc[rg][1][r]);
          }
        }
    }
  }
}

// ---- classifier -----------------------------------------------------------

__global__ __launch_bounds__(128) void k_cls1(const float* __restrict__ gsum, const int* __restrict__ gcnt,
                                              const float* __restrict__ Wc1, const float* __restrict__ bc1,
                                              float* __restrict__ z) {
  int g = blockIdx.x;
  int h = threadIdx.x;
  float inv = 1.0f / (float)max(gcnt[g], 1);
  float s = 0.f;
  for (int f = 0; f < 128; ++f) s += gsum[g * 128 + f] * Wc1[h * 128 + f];
  z[g * 128 + h] = fmaxf(s * inv + bc1[h], 0.f);
}

__global__ __launch_bounds__(128) void k_cls2(const float* __restrict__ z, const float* __restrict__ Wc2,
                                              const float* __restrict__ bc2, float* __restrict__ out) {
  __shared__ float red[128];
  int g = blockIdx.x;
  int t = threadIdx.x;
  red[t] = z[g * 128 + t] * Wc2[t];
  __syncthreads();
  for (int d = 64; d > 0; d >>= 1) {
    if (t < d) red[t] += red[t + d];
    __syncthreads();
  }
  if (t == 0) out[g] = red[0] + bc2[0];
}

// ---------------------------------------------------------------------------

extern "C" void kernel_launch(void* const* d_in, const int* in_sizes, int n_in,
                              void* d_out, int out_size, void* d_ws, size_t ws_size,
                              hipStream_t stream) {
  const float* x   = (const float*)d_in[0];
  const int*   ei  = (const int*)d_in[1];
  const int*   bat = (const int*)d_in[2];
  const float* W1l = (const float*)d_in[3];
  const float* b1l = (const float*)d_in[4];
  const float* W1r = (const float*)d_in[5];
  const float* W2l = (const float*)d_in[6];
  const float* b2l = (const float*)d_in[7];
  const float* W2r = (const float*)d_in[8];
  const float* Wc1 = (const float*)d_in[9];
  const float* bc1 = (const float*)d_in[10];
  const float* Wc2 = (const float*)d_in[11];
  const float* bc2 = (const float*)d_in[12];
  float* out = (float*)d_out;

  int N = in_sizes[0] / 128;
  int E = in_sizes[1] / 2;
  int nEblk = (E + HBLK - 1) / HBLK;        // 147
  int nBuk = (N + 255) >> 8;                // 196

  char* ws = (char*)d_ws;
  size_t o = 0;
  auto alloc = [&](size_t bytes) {
    char* p = ws + o;
    o += (bytes + 255) & ~(size_t)255;
    return p;
  };
  int*      off    = (int*)alloc((size_t)(N + 1) * 4);
  int*      col    = (int*)alloc((size_t)E * 4);
  unsigned* ebuk   = (unsigned*)alloc((size_t)E * 4);
  int*      bhist  = (int*)alloc((size_t)nEblk * 256 * 4);
  int*      bukbase= (int*)alloc(257 * 4);
  float*    T      = (float*)alloc((size_t)N * 128 * 4);
  float*    h1     = (float*)alloc((size_t)N * 128 * 4);
  unsigned short* xbf = (unsigned short*)alloc((size_t)N * 128 * 2);  // reused as h1bf
  unsigned short* Bpre1 = (unsigned short*)alloc(65536 * 2);
  unsigned short* Bpre2 = (unsigned short*)alloc(65536 * 2);
  float*    gsum   = (float*)alloc(64 * 128 * 4 + 64 * 4);
  int*      gcnt   = (int*)(gsum + 64 * 128);
  float*    z      = (float*)alloc(64 * 128 * 4);

  hipMemsetAsync(gsum, 0, 64 * 128 * 4, stream);

  // prep
  k_tobf<<<(N * 128 / 4 + 255) / 256, 256, 0, stream>>>(x, xbf, N * 128);
  k_wprep<<<16, 256, 0, stream>>>(W1l, W1r, Bpre1);
  k_wprep<<<16, 256, 0, stream>>>(W2l, W2r, Bpre2);
  k_gcnt_bs<<<1, 64, 0, stream>>>(bat, gcnt, N, 64);

  // CSR build (counting sort, LDS atomics only)
  k_hist<<<nEblk, 256, 0, stream>>>(ei, bhist, E);
  k_bscan<<<1, 256, 0, stream>>>(bhist, bukbase, nEblk, E);
  k_scat<<<nEblk, 256, 0, stream>>>(ei, bhist, ebuk, E);
  k_bucket<<<nBuk, 256, 0, stream>>>(ebuk, bukbase, off, col, N, E);

  int nLinBlk = (N + 63) / 64;
  // layer 1 (gather bf16 x; lin writes h1 fp32 + h1bf into xbf buffer)
  k_agg_bf<<<(N + 3) / 4, 256, 0, stream>>>(xbf, off, col, T, N);
  k_lin_mfma<<<nLinBlk, 256, 0, stream>>>(T, x, Bpre1, b1l, h1, xbf, bat, gsum, N, 0);
  // layer 2 (gather bf16 h1; pooled in epilogue, h2 never materialized)
  k_agg_bf<<<(N + 3) / 4, 256, 0, stream>>>(xbf, off, col, T, N);
  k_lin_mfma<<<nLinBlk, 256, 0, stream>>>(T, h1, Bpre2, b2l, nullptr, nullptr, bat, gsum, N, 1);

  // classifier
  k_cls1<<<64, 128, 0, stream>>>(gsum, gcnt, Wc1, bc1, z);
  k_cls2<<<64, 128, 0, stream>>>(z, Wc2, bc2, out);
}